// Round 1
// baseline (5023.843 us; speedup 1.0000x reference)
//
#include <hip/hip_runtime.h>
#include <hip/hip_bf16.h>

// ---------------------------------------------------------------------------
// StackGCNEncoder on MI355X — round 1: correct fp32 implementation.
//
// Pipeline per layer:
//   Y = H @ [Wcat | SW]            (one fp32 GEMM per side; Y = [tmp | base])
//   base[r, s*k+ch] += v * tmp_other[c, s*k+ch]   (atomic scatter per edge)
//   H' = relu(base)
// Layer-1 output Z is aliased into Y cols [0,512) (GEMM reads cols [512,1024),
// writes cols [0,512) — disjoint, safe).
//
// Workspace layout (floats):
//   Yrna  : 50000*1024
//   Yprot : 20000*1024
//   B0    : 1024*1024   (packed [w0 | sw0])
//   B1    : 512*512     (packed [w1 | sw1])
// total ~292 MB.
// ---------------------------------------------------------------------------

#define GEMM_BM 64
#define GEMM_BN 64
#define GEMM_BK 16

__global__ __launch_bounds__(256)
void gemm_f32_kernel(const float* __restrict__ A, int lda,
                     const float* __restrict__ B, int ldb,
                     float* __restrict__ C, int ldc,
                     int M, int N, int K)
{
    // As transposed [k][m], padded +4 so rows stay 16B-aligned for b128 reads
    __shared__ float As[GEMM_BK][GEMM_BM + 4];
    __shared__ float Bs[GEMM_BK][GEMM_BN];

    const int tid = threadIdx.x;
    const int tx  = tid & 15;       // n-dir thread
    const int ty  = tid >> 4;       // m-dir thread
    const int bm0 = blockIdx.y * GEMM_BM;
    const int bn0 = blockIdx.x * GEMM_BN;

    const int arow = tid >> 2;           // 0..63
    const int acol = (tid & 3) * 4;      // 0,4,8,12
    const int brow = tid >> 4;           // 0..15
    const int bcol = (tid & 15) * 4;     // 0..60

    float acc[4][4] = {};

    for (int k0 = 0; k0 < K; k0 += GEMM_BK) {
        float4 a4 = make_float4(0.f, 0.f, 0.f, 0.f);
        if (bm0 + arow < M)
            a4 = *(const float4*)(A + (size_t)(bm0 + arow) * lda + k0 + acol);
        float4 b4 = *(const float4*)(B + (size_t)(k0 + brow) * ldb + bn0 + bcol);

        __syncthreads();
        As[acol + 0][arow] = a4.x;
        As[acol + 1][arow] = a4.y;
        As[acol + 2][arow] = a4.z;
        As[acol + 3][arow] = a4.w;
        *(float4*)&Bs[brow][bcol] = b4;
        __syncthreads();

        #pragma unroll
        for (int kk = 0; kk < GEMM_BK; ++kk) {
            float4 av = *(const float4*)&As[kk][ty * 4];
            float4 bv = *(const float4*)&Bs[kk][tx * 4];
            float a[4] = {av.x, av.y, av.z, av.w};
            float b[4] = {bv.x, bv.y, bv.z, bv.w};
            #pragma unroll
            for (int i = 0; i < 4; ++i)
                #pragma unroll
                for (int j = 0; j < 4; ++j)
                    acc[i][j] += a[i] * b[j];
        }
    }

    #pragma unroll
    for (int i = 0; i < 4; ++i) {
        int m = bm0 + ty * 4 + i;
        if (m < M) {
            float4 o = make_float4(acc[i][0], acc[i][1], acc[i][2], acc[i][3]);
            *(float4*)(C + (size_t)m * ldc + bn0 + tx * 4) = o;
        }
    }
}

// One thread per (edge, channel). grid = (E*KCH/256, S).
template<int KCH>
__global__ __launch_bounds__(256)
void scatter_add_kernel(const int* __restrict__ rows,
                        const int* __restrict__ cols,
                        const float* __restrict__ vals,
                        const float* __restrict__ In, int ldi,
                        float* __restrict__ Out, int ldo, int ocol,
                        int E)
{
    const int s  = blockIdx.y;
    const int g  = blockIdx.x * 256 + threadIdx.x;   // [0, E*KCH)
    const int ch = g & (KCH - 1);
    const int e  = g / KCH;                          // compile-time shift
    const int idx = s * E + e;
    const int r  = rows[idx];
    const int c  = cols[idx];
    const float v = vals[idx];
    const int col = s * KCH + ch;
    atomicAdd(Out + (size_t)r * ldo + ocol + col, v * In[(size_t)c * ldi + col]);
}

template<int NC>
__global__ __launch_bounds__(256)
void relu_inplace_kernel(float* __restrict__ Y, int ld, int coff, int M)
{
    int g = blockIdx.x * 256 + threadIdx.x;
    if (g >= M * NC) return;
    int row = g / NC;          // NC power-of-2 -> shift
    int col = g & (NC - 1);
    float* p = Y + (size_t)row * ld + coff + col;
    float x = *p;
    *p = x > 0.f ? x : 0.f;
}

template<int NC>
__global__ __launch_bounds__(256)
void relu_out_kernel(const float* __restrict__ Z, int ld, int coff,
                     float* __restrict__ out, int M)
{
    int g = blockIdx.x * 256 + threadIdx.x;
    if (g >= M * NC) return;
    int row = g / NC;
    int col = g & (NC - 1);
    float x = Z[(size_t)row * ld + coff + col];
    out[g] = fmaxf(x, 0.f);
}

// B0[d][j]: j<512 -> w0[j>>7][d][j&127]; else sw0[d][j-512].  (1024x1024)
__global__ __launch_bounds__(256)
void pack_b0_kernel(const float* __restrict__ w0, const float* __restrict__ sw0,
                    float* __restrict__ B0)
{
    int g = blockIdx.x * 256 + threadIdx.x;   // < 1024*1024
    int d = g >> 10, j = g & 1023;
    float v;
    if (j < 512) {
        int s = j >> 7, kk = j & 127;
        v = w0[((size_t)s * 1024 + d) * 128 + kk];
    } else {
        v = sw0[(size_t)d * 512 + (j - 512)];
    }
    B0[g] = v;
}

// B1[d][j]: j<256 -> w1[j>>6][d][j&63]; else sw1[d][j-256].   (512x512)
__global__ __launch_bounds__(256)
void pack_b1_kernel(const float* __restrict__ w1, const float* __restrict__ sw1,
                    float* __restrict__ B1)
{
    int g = blockIdx.x * 256 + threadIdx.x;   // < 512*512
    int d = g >> 9, j = g & 511;
    float v;
    if (j < 256) {
        int s = j >> 6, kk = j & 63;
        v = w1[((size_t)s * 512 + d) * 64 + kk];
    } else {
        v = sw1[(size_t)d * 256 + (j - 256)];
    }
    B1[g] = v;
}

extern "C" void kernel_launch(void* const* d_in, const int* in_sizes, int n_in,
                              void* d_out, int out_size, void* d_ws, size_t ws_size,
                              hipStream_t stream)
{
    const int*   rna_rows  = (const int*)  d_in[0];
    const int*   rna_cols  = (const int*)  d_in[1];
    const float* rna_vals  = (const float*)d_in[2];
    const int*   prot_rows = (const int*)  d_in[3];
    const int*   prot_cols = (const int*)  d_in[4];
    const float* prot_vals = (const float*)d_in[5];
    const float* H_rna     = (const float*)d_in[6];
    const float* H_prot    = (const float*)d_in[7];
    const float* w0        = (const float*)d_in[8];
    const float* sw0       = (const float*)d_in[9];
    const float* w1        = (const float*)d_in[10];
    const float* sw1       = (const float*)d_in[11];

    const int NRNA = 50000, NPROT = 20000, S = 4, E = 500000;

    float* Yrna  = (float*)d_ws;
    float* Yprot = Yrna  + (size_t)NRNA  * 1024;
    float* B0    = Yprot + (size_t)NPROT * 1024;
    float* B1    = B0 + 1024 * 1024;

    dim3 blk(256);

    // --- pack weights ---
    pack_b0_kernel<<<(1024 * 1024) / 256, blk, 0, stream>>>(w0, sw0, B0);
    pack_b1_kernel<<<(512 * 512) / 256, blk, 0, stream>>>(w1, sw1, B1);

    // --- layer 0: Y = H @ [W0cat | SW0]  (N=K=1024) ---
    {
        dim3 grid(1024 / GEMM_BN, (NRNA + GEMM_BM - 1) / GEMM_BM);
        gemm_f32_kernel<<<grid, blk, 0, stream>>>(H_rna, 1024, B0, 1024,
                                                  Yrna, 1024, NRNA, 1024, 1024);
        dim3 grid2(1024 / GEMM_BN, (NPROT + GEMM_BM - 1) / GEMM_BM);
        gemm_f32_kernel<<<grid2, blk, 0, stream>>>(H_prot, 1024, B0, 1024,
                                                   Yprot, 1024, NPROT, 1024, 1024);
    }
    // --- layer 0 scatter: base += v * tmp_other ---
    {
        dim3 g1((E * 128) / 256, S);
        scatter_add_kernel<128><<<g1, blk, 0, stream>>>(
            rna_rows, rna_cols, rna_vals, Yprot, 1024, Yrna, 1024, 512, E);
        scatter_add_kernel<128><<<g1, blk, 0, stream>>>(
            prot_rows, prot_cols, prot_vals, Yrna, 1024, Yprot, 1024, 512, E);
    }
    // --- layer 0 relu (in place on cols 512..1023) ---
    relu_inplace_kernel<512><<<(NRNA * 512) / 256, blk, 0, stream>>>(Yrna, 1024, 512, NRNA);
    relu_inplace_kernel<512><<<(NPROT * 512) / 256, blk, 0, stream>>>(Yprot, 1024, 512, NPROT);

    // --- layer 1: Z = H1 @ [W1cat | SW1]  (N=K=512), Z aliased into Y cols 0..511 ---
    {
        dim3 grid(512 / GEMM_BN, (NRNA + GEMM_BM - 1) / GEMM_BM);
        gemm_f32_kernel<<<grid, blk, 0, stream>>>(Yrna + 512, 1024, B1, 512,
                                                  Yrna, 1024, NRNA, 512, 512);
        dim3 grid2(512 / GEMM_BN, (NPROT + GEMM_BM - 1) / GEMM_BM);
        gemm_f32_kernel<<<grid2, blk, 0, stream>>>(Yprot + 512, 1024, B1, 512,
                                                   Yprot, 1024, NPROT, 512, 512);
    }
    // --- layer 1 scatter (k=64, base at cols 256..511) ---
    {
        dim3 g1((E * 64) / 256, S);
        scatter_add_kernel<64><<<g1, blk, 0, stream>>>(
            rna_rows, rna_cols, rna_vals, Yprot, 1024, Yrna, 1024, 256, E);
        scatter_add_kernel<64><<<g1, blk, 0, stream>>>(
            prot_rows, prot_cols, prot_vals, Yrna, 1024, Yprot, 1024, 256, E);
    }
    // --- final relu -> d_out (f32, [50000*256] then [20000*256]) ---
    float* out = (float*)d_out;
    relu_out_kernel<256><<<(NRNA * 256) / 256, blk, 0, stream>>>(Yrna, 1024, 256, out, NRNA);
    relu_out_kernel<256><<<(NPROT * 256) / 256, blk, 0, stream>>>(Yprot, 1024, 256,
                                                                  out + (size_t)NRNA * 256, NPROT);
}

// Round 2
// 3377.502 us; speedup vs baseline: 1.4874x; 1.4874x over previous
//
#include <hip/hip_runtime.h>
#include <hip/hip_bf16.h>

// ---------------------------------------------------------------------------
// StackGCNEncoder on MI355X — round 2: split-bf16 MFMA GEMM (bf16x3).
//
// Per layer:
//   [Ahi|Alo] = split(H)                    (f32 -> hi/lo bf16)
//   Y = A @ [Wcat | SW]  via MFMA:  AhiBhi + AhiBlo + AloBhi
//   base[r, s*k+ch] += v * tmp_other[c, s*k+ch]   (atomic scatter per edge)
//   H' = relu(base)  (fused into next split)
//
// Workspace (elements):
//   Yrna  f32 50000*1024      Yprot f32 20000*1024
//   Ah,Al u16 50048*1024 each (shared/reused across all 4 GEMM inputs)
//   B0h,B0l u16 1024*1024 ([N][K] transposed)   B1h,B1l u16 512*512
// total ~497 MB.
// ---------------------------------------------------------------------------

typedef unsigned short u16;
typedef short s16x8 __attribute__((ext_vector_type(8)));
typedef float f32x4 __attribute__((ext_vector_type(4)));
typedef __attribute__((ext_vector_type(4))) unsigned short u16x4;

__device__ __forceinline__ u16 f2bf(float x) {            // RNE f32->bf16
    unsigned u = __float_as_uint(x);
    return (u16)((u + 0x7fff + ((u >> 16) & 1)) >> 16);
}
__device__ __forceinline__ float bf2f(u16 h) {
    return __uint_as_float(((unsigned)h) << 16);
}

__device__ __forceinline__ void gload16(const u16* g, u16* l) {
    __builtin_amdgcn_global_load_lds(
        (const __attribute__((address_space(1))) unsigned int*)g,
        (__attribute__((address_space(3))) unsigned int*)l,
        16, 0, 0);
}

// ---------------------------------------------------------------------------
// Split-bf16 GEMM: C[M][N](f32,ldc) = A[Mpad][K] x B^T[N][K], all tiles 128x128xBK32.
// A,B given as hi/lo bf16 pairs. grid = (N/128, Mpad/128), 256 threads.
// ---------------------------------------------------------------------------
__global__ __launch_bounds__(256)
void gemm_split_kernel(const u16* __restrict__ Ah, const u16* __restrict__ Al,
                       const u16* __restrict__ Bh, const u16* __restrict__ Bl,
                       float* __restrict__ C, int ldc,
                       int M, int K)
{
    __shared__ u16 lds[2][4][128 * 32];   // [buf][Ah,Al,Bh,Bl][tile] = 64 KB

    const int tid  = threadIdx.x;
    const int lane = tid & 63;
    const int wid  = tid >> 6;
    const int wr   = wid >> 1;            // wave row (0..1) -> 64 rows
    const int wc   = wid & 1;             // wave col (0..1) -> 64 cols
    const int bm0  = blockIdx.y * 128;
    const int bn0  = blockIdx.x * 128;

    // staging: thread t covers 16B chunk at row (t>>2)(+64), col (t&3)*8
    const int srow = tid >> 2;
    const int scol = (tid & 3) * 8;
    const size_t aoff0 = (size_t)(bm0 + srow) * K + scol;
    const size_t aoff1 = (size_t)(bm0 + srow + 64) * K + scol;
    const size_t boff0 = (size_t)(bn0 + srow) * K + scol;
    const size_t boff1 = (size_t)(bn0 + srow + 64) * K + scol;
    const int c0 = tid * 8;               // lds offset (u16 units)
    const int c1 = 2048 + tid * 8;

    u16* L0 = &lds[0][0][0];

    f32x4 zero = {0.f, 0.f, 0.f, 0.f};
    f32x4 acc[4][4];
    #pragma unroll
    for (int i = 0; i < 4; ++i)
        #pragma unroll
        for (int j = 0; j < 4; ++j) acc[i][j] = zero;

    // fragment lds offsets (u16 units), frag mf/nf adds mf*512
    const int a_fr = (wr * 64 + (lane & 15)) * 32 + (lane >> 4) * 8;
    const int b_fr = (wc * 64 + (lane & 15)) * 32 + (lane >> 4) * 8;

    const int nk = K >> 5;   // K/32

    // prologue: stage tile 0 into buf 0
    {
        u16* L = L0;
        gload16(Ah + aoff0, L + c0);            gload16(Ah + aoff1, L + c1);
        gload16(Al + aoff0, L + 4096 + c0);     gload16(Al + aoff1, L + 4096 + c1);
        gload16(Bh + boff0, L + 8192 + c0);     gload16(Bh + boff1, L + 8192 + c1);
        gload16(Bl + boff0, L + 12288 + c0);    gload16(Bl + boff1, L + 12288 + c1);
    }

    int cur = 0;
    for (int t = 0; t < nk; ++t) {
        __syncthreads();   // buf[cur] staged; prev reads of buf[cur^1] done
        if (t + 1 < nk) {
            const int k0 = (t + 1) * 32;
            u16* L = L0 + (cur ^ 1) * 16384;
            gload16(Ah + aoff0 + k0, L + c0);         gload16(Ah + aoff1 + k0, L + c1);
            gload16(Al + aoff0 + k0, L + 4096 + c0);  gload16(Al + aoff1 + k0, L + 4096 + c1);
            gload16(Bh + boff0 + k0, L + 8192 + c0);  gload16(Bh + boff1 + k0, L + 8192 + c1);
            gload16(Bl + boff0 + k0, L + 12288 + c0); gload16(Bl + boff1 + k0, L + 12288 + c1);
        }
        const u16* L = L0 + cur * 16384;
        s16x8 bh[4], bl[4];
        #pragma unroll
        for (int nf = 0; nf < 4; ++nf) {
            const int o = b_fr + nf * 512;
            bh[nf] = *(const s16x8*)(L + 8192 + o);
            bl[nf] = *(const s16x8*)(L + 12288 + o);
        }
        #pragma unroll
        for (int mf = 0; mf < 4; ++mf) {
            const int o = a_fr + mf * 512;
            s16x8 ahv = *(const s16x8*)(L + o);
            s16x8 alv = *(const s16x8*)(L + 4096 + o);
            #pragma unroll
            for (int nf = 0; nf < 4; ++nf) {
                acc[mf][nf] = __builtin_amdgcn_mfma_f32_16x16x32_bf16(ahv, bh[nf], acc[mf][nf], 0, 0, 0);
                acc[mf][nf] = __builtin_amdgcn_mfma_f32_16x16x32_bf16(ahv, bl[nf], acc[mf][nf], 0, 0, 0);
                acc[mf][nf] = __builtin_amdgcn_mfma_f32_16x16x32_bf16(alv, bh[nf], acc[mf][nf], 0, 0, 0);
            }
        }
        cur ^= 1;
    }

    // C write: row = bm0+wr*64+mf*16+(lane>>4)*4+r ; col = bn0+wc*64+nf*16+(lane&15)
    #pragma unroll
    for (int mf = 0; mf < 4; ++mf) {
        const int row0 = bm0 + wr * 64 + mf * 16 + (lane >> 4) * 4;
        #pragma unroll
        for (int nf = 0; nf < 4; ++nf) {
            const int col = bn0 + wc * 64 + nf * 16 + (lane & 15);
            #pragma unroll
            for (int r = 0; r < 4; ++r) {
                if (row0 + r < M)
                    C[(size_t)(row0 + r) * ldc + col] = acc[mf][nf][r];
            }
        }
    }
}

// ---------------------------------------------------------------------------
// f32 [M][K] -> hi/lo bf16 [Mpad][K], zero-padded rows. 4 elems/thread.
// kshift = log2(K). grid covers Mpad*K/4 threads.
// ---------------------------------------------------------------------------
__global__ __launch_bounds__(256)
void split_kernel(const float* __restrict__ A, u16* __restrict__ Hh,
                  u16* __restrict__ Hl, int M, int kshift)
{
    const size_t g  = (size_t)blockIdx.x * 256 + threadIdx.x;
    const size_t i4 = g * 4;
    const int row   = (int)(i4 >> kshift);
    f32x4 v = {0.f, 0.f, 0.f, 0.f};
    if (row < M) v = *(const f32x4*)(A + i4);
    u16x4 h, l;
    #pragma unroll
    for (int j = 0; j < 4; ++j) {
        u16 hb = f2bf(v[j]);
        h[j] = hb;
        l[j] = f2bf(v[j] - bf2f(hb));
    }
    *(u16x4*)(Hh + i4) = h;
    *(u16x4*)(Hl + i4) = l;
}

// relu(Y[row][coff..coff+512)) -> hi/lo bf16 [Mpad][512]
__global__ __launch_bounds__(256)
void relu_split_kernel(const float* __restrict__ Y, int ld, int coff,
                       u16* __restrict__ Hh, u16* __restrict__ Hl, int M)
{
    const size_t g  = (size_t)blockIdx.x * 256 + threadIdx.x;
    const size_t i4 = g * 4;
    const int row   = (int)(i4 >> 9);
    const int col   = (int)(i4 & 511);
    f32x4 v = {0.f, 0.f, 0.f, 0.f};
    if (row < M) v = *(const f32x4*)(Y + (size_t)row * ld + coff + col);
    u16x4 h, l;
    #pragma unroll
    for (int j = 0; j < 4; ++j) {
        float x = fmaxf(v[j], 0.f);
        u16 hb = f2bf(x);
        h[j] = hb;
        l[j] = f2bf(x - bf2f(hb));
    }
    *(u16x4*)(Hh + i4) = h;
    *(u16x4*)(Hl + i4) = l;
}

// ---------------------------------------------------------------------------
// scatter: one thread per (edge, channel). grid = (E*KCH/256, S).
// ---------------------------------------------------------------------------
template<int KCH>
__global__ __launch_bounds__(256)
void scatter_add_kernel(const int* __restrict__ rows,
                        const int* __restrict__ cols,
                        const float* __restrict__ vals,
                        const float* __restrict__ In, int ldi,
                        float* __restrict__ Out, int ldo, int ocol,
                        int E)
{
    const int s  = blockIdx.y;
    const int g  = blockIdx.x * 256 + threadIdx.x;
    const int ch = g & (KCH - 1);
    const int e  = g / KCH;
    const int idx = s * E + e;
    const int r  = rows[idx];
    const int c  = cols[idx];
    const float v = vals[idx];
    const int col = s * KCH + ch;
    atomicAdd(Out + (size_t)r * ldo + ocol + col, v * In[(size_t)c * ldi + col]);
}

template<int NC>
__global__ __launch_bounds__(256)
void relu_out_kernel(const float* __restrict__ Z, int ld, int coff,
                     float* __restrict__ out, int M)
{
    int g = blockIdx.x * 256 + threadIdx.x;
    if (g >= M * NC) return;
    int row = g / NC;
    int col = g & (NC - 1);
    float x = Z[(size_t)row * ld + coff + col];
    out[g] = fmaxf(x, 0.f);
}

// B0t[j][d] (transposed, [N=1024][K=1024]) hi/lo
__global__ __launch_bounds__(256)
void pack_b0_split_kernel(const float* __restrict__ w0, const float* __restrict__ sw0,
                          u16* __restrict__ Bh, u16* __restrict__ Bl)
{
    int g = blockIdx.x * 256 + threadIdx.x;   // < 1024*1024
    int j = g >> 10, d = g & 1023;
    float v;
    if (j < 512) v = w0[((size_t)(j >> 7) * 1024 + d) * 128 + (j & 127)];
    else         v = sw0[(size_t)d * 512 + (j - 512)];
    u16 h = f2bf(v);
    Bh[g] = h;
    Bl[g] = f2bf(v - bf2f(h));
}

// B1t[j][d] ([N=512][K=512]) hi/lo
__global__ __launch_bounds__(256)
void pack_b1_split_kernel(const float* __restrict__ w1, const float* __restrict__ sw1,
                          u16* __restrict__ Bh, u16* __restrict__ Bl)
{
    int g = blockIdx.x * 256 + threadIdx.x;   // < 512*512
    int j = g >> 9, d = g & 511;
    float v;
    if (j < 256) v = w1[((size_t)(j >> 6) * 512 + d) * 64 + (j & 63)];
    else         v = sw1[(size_t)d * 256 + (j - 256)];
    u16 h = f2bf(v);
    Bh[g] = h;
    Bl[g] = f2bf(v - bf2f(h));
}

extern "C" void kernel_launch(void* const* d_in, const int* in_sizes, int n_in,
                              void* d_out, int out_size, void* d_ws, size_t ws_size,
                              hipStream_t stream)
{
    const int*   rna_rows  = (const int*)  d_in[0];
    const int*   rna_cols  = (const int*)  d_in[1];
    const float* rna_vals  = (const float*)d_in[2];
    const int*   prot_rows = (const int*)  d_in[3];
    const int*   prot_cols = (const int*)  d_in[4];
    const float* prot_vals = (const float*)d_in[5];
    const float* H_rna     = (const float*)d_in[6];
    const float* H_prot    = (const float*)d_in[7];
    const float* w0        = (const float*)d_in[8];
    const float* sw0       = (const float*)d_in[9];
    const float* w1        = (const float*)d_in[10];
    const float* sw1       = (const float*)d_in[11];

    const int NRNA = 50000, NPROT = 20000, S = 4, E = 500000;
    const int MP_RNA = 50048, MP_PROT = 20096;   // padded to x128

    float* Yrna  = (float*)d_ws;
    float* Yprot = Yrna  + (size_t)NRNA  * 1024;
    u16*   Ah    = (u16*)(Yprot + (size_t)NPROT * 1024);
    u16*   Al    = Ah  + (size_t)MP_RNA * 1024;
    u16*   B0h   = Al  + (size_t)MP_RNA * 1024;
    u16*   B0l   = B0h + 1024 * 1024;
    u16*   B1h   = B0l + 1024 * 1024;
    u16*   B1l   = B1h + 512 * 512;

    dim3 blk(256);

    // --- pack weights (hi/lo, transposed [N][K]) ---
    pack_b0_split_kernel<<<(1024 * 1024) / 256, blk, 0, stream>>>(w0, sw0, B0h, B0l);
    pack_b1_split_kernel<<<(512 * 512) / 256, blk, 0, stream>>>(w1, sw1, B1h, B1l);

    // --- layer 0 rna: split + GEMM (N=K=1024) ---
    split_kernel<<<MP_RNA, blk, 0, stream>>>(H_rna, Ah, Al, NRNA, 10);
    {
        dim3 grid(1024 / 128, MP_RNA / 128);
        gemm_split_kernel<<<grid, blk, 0, stream>>>(Ah, Al, B0h, B0l, Yrna, 1024, NRNA, 1024);
    }
    // --- layer 0 prot ---
    split_kernel<<<MP_PROT, blk, 0, stream>>>(H_prot, Ah, Al, NPROT, 10);
    {
        dim3 grid(1024 / 128, MP_PROT / 128);
        gemm_split_kernel<<<grid, blk, 0, stream>>>(Ah, Al, B0h, B0l, Yprot, 1024, NPROT, 1024);
    }
    // --- layer 0 scatter: base(cols 512..1023) += v * tmp_other(cols 0..511) ---
    {
        dim3 g1((E * 128) / 256, S);
        scatter_add_kernel<128><<<g1, blk, 0, stream>>>(
            rna_rows, rna_cols, rna_vals, Yprot, 1024, Yrna, 1024, 512, E);
        scatter_add_kernel<128><<<g1, blk, 0, stream>>>(
            prot_rows, prot_cols, prot_vals, Yrna, 1024, Yprot, 1024, 512, E);
    }
    // --- layer 1 rna: relu+split + GEMM (N=K=512, C into Y cols 0..511) ---
    relu_split_kernel<<<MP_RNA / 2, blk, 0, stream>>>(Yrna, 1024, 512, Ah, Al, NRNA);
    {
        dim3 grid(512 / 128, MP_RNA / 128);
        gemm_split_kernel<<<grid, blk, 0, stream>>>(Ah, Al, B1h, B1l, Yrna, 1024, NRNA, 512);
    }
    // --- layer 1 prot ---
    relu_split_kernel<<<MP_PROT / 2, blk, 0, stream>>>(Yprot, 1024, 512, Ah, Al, NPROT);
    {
        dim3 grid(512 / 128, MP_PROT / 128);
        gemm_split_kernel<<<grid, blk, 0, stream>>>(Ah, Al, B1h, B1l, Yprot, 1024, NPROT, 512);
    }
    // --- layer 1 scatter (k=64, base at cols 256..511) ---
    {
        dim3 g1((E * 64) / 256, S);
        scatter_add_kernel<64><<<g1, blk, 0, stream>>>(
            rna_rows, rna_cols, rna_vals, Yprot, 1024, Yrna, 1024, 256, E);
        scatter_add_kernel<64><<<g1, blk, 0, stream>>>(
            prot_rows, prot_cols, prot_vals, Yrna, 1024, Yprot, 1024, 256, E);
    }
    // --- final relu -> d_out ---
    float* out = (float*)d_out;
    relu_out_kernel<256><<<(NRNA * 256) / 256, blk, 0, stream>>>(Yrna, 1024, 256, out, NRNA);
    relu_out_kernel<256><<<(NPROT * 256) / 256, blk, 0, stream>>>(Yprot, 1024, 256,
                                                                  out + (size_t)NRNA * 256, NPROT);
}

// Round 3
// 1834.755 us; speedup vs baseline: 2.7382x; 1.8408x over previous
//
#include <hip/hip_runtime.h>
#include <hip/hip_bf16.h>

// ---------------------------------------------------------------------------
// StackGCNEncoder on MI355X — round 3: CSR-based SpMM (no atomics in hot path).
//
// Per layer:
//   [Ahi|Alo] = split(H);  Y = A @ [Wcat | SW]  (split-bf16 MFMA GEMM)
//   CSR-SpMM:  base[r, :] += sum_e v_e * tmp_other[c_e, :]   (owner-computes)
//   H' = relu(base)
// CSR for both sides is built ONCE per call (histogram + scan + cursor fill)
// and reused by both layers. CSR arrays live in d_out (dead until final relu).
//
// Workspace (same 497 MB as round 2):
//   Yrna f32 50000*1024 | Yprot f32 20000*1024 | Ah,Al u16 50048*1024
//   B0h,B0l u16 1024^2 | B1h,B1l u16 512^2
// d_out scratch (35.4 MB of 71.7 MB): colsrt/valsrt (S*E each side) + meta.
// ---------------------------------------------------------------------------

typedef unsigned short u16;
typedef short s16x8 __attribute__((ext_vector_type(8)));
typedef float f32x4 __attribute__((ext_vector_type(4)));
typedef __attribute__((ext_vector_type(4))) unsigned short u16x4;

__device__ __forceinline__ u16 f2bf(float x) {            // RNE f32->bf16
    unsigned u = __float_as_uint(x);
    return (u16)((u + 0x7fff + ((u >> 16) & 1)) >> 16);
}
__device__ __forceinline__ float bf2f(u16 h) {
    return __uint_as_float(((unsigned)h) << 16);
}

__device__ __forceinline__ void gload16(const u16* g, u16* l) {
    __builtin_amdgcn_global_load_lds(
        (const __attribute__((address_space(1))) unsigned int*)g,
        (__attribute__((address_space(3))) unsigned int*)l,
        16, 0, 0);
}

// ---------------------------------------------------------------------------
// Split-bf16 GEMM (verified round 2): C[M][N] = A[Mpad][K] x B^T[N][K].
// ---------------------------------------------------------------------------
__global__ __launch_bounds__(256)
void gemm_split_kernel(const u16* __restrict__ Ah, const u16* __restrict__ Al,
                       const u16* __restrict__ Bh, const u16* __restrict__ Bl,
                       float* __restrict__ C, int ldc,
                       int M, int K)
{
    __shared__ u16 lds[2][4][128 * 32];   // 64 KB

    const int tid  = threadIdx.x;
    const int lane = tid & 63;
    const int wid  = tid >> 6;
    const int wr   = wid >> 1;
    const int wc   = wid & 1;
    const int bm0  = blockIdx.y * 128;
    const int bn0  = blockIdx.x * 128;

    const int srow = tid >> 2;
    const int scol = (tid & 3) * 8;
    const size_t aoff0 = (size_t)(bm0 + srow) * K + scol;
    const size_t aoff1 = (size_t)(bm0 + srow + 64) * K + scol;
    const size_t boff0 = (size_t)(bn0 + srow) * K + scol;
    const size_t boff1 = (size_t)(bn0 + srow + 64) * K + scol;
    const int c0 = tid * 8;
    const int c1 = 2048 + tid * 8;

    u16* L0 = &lds[0][0][0];

    f32x4 zero = {0.f, 0.f, 0.f, 0.f};
    f32x4 acc[4][4];
    #pragma unroll
    for (int i = 0; i < 4; ++i)
        #pragma unroll
        for (int j = 0; j < 4; ++j) acc[i][j] = zero;

    const int a_fr = (wr * 64 + (lane & 15)) * 32 + (lane >> 4) * 8;
    const int b_fr = (wc * 64 + (lane & 15)) * 32 + (lane >> 4) * 8;

    const int nk = K >> 5;

    {
        u16* L = L0;
        gload16(Ah + aoff0, L + c0);            gload16(Ah + aoff1, L + c1);
        gload16(Al + aoff0, L + 4096 + c0);     gload16(Al + aoff1, L + 4096 + c1);
        gload16(Bh + boff0, L + 8192 + c0);     gload16(Bh + boff1, L + 8192 + c1);
        gload16(Bl + boff0, L + 12288 + c0);    gload16(Bl + boff1, L + 12288 + c1);
    }

    int cur = 0;
    for (int t = 0; t < nk; ++t) {
        __syncthreads();
        if (t + 1 < nk) {
            const int k0 = (t + 1) * 32;
            u16* L = L0 + (cur ^ 1) * 16384;
            gload16(Ah + aoff0 + k0, L + c0);         gload16(Ah + aoff1 + k0, L + c1);
            gload16(Al + aoff0 + k0, L + 4096 + c0);  gload16(Al + aoff1 + k0, L + 4096 + c1);
            gload16(Bh + boff0 + k0, L + 8192 + c0);  gload16(Bh + boff1 + k0, L + 8192 + c1);
            gload16(Bl + boff0 + k0, L + 12288 + c0); gload16(Bl + boff1 + k0, L + 12288 + c1);
        }
        const u16* L = L0 + cur * 16384;
        s16x8 bh[4], bl[4];
        #pragma unroll
        for (int nf = 0; nf < 4; ++nf) {
            const int o = b_fr + nf * 512;
            bh[nf] = *(const s16x8*)(L + 8192 + o);
            bl[nf] = *(const s16x8*)(L + 12288 + o);
        }
        #pragma unroll
        for (int mf = 0; mf < 4; ++mf) {
            const int o = a_fr + mf * 512;
            s16x8 ahv = *(const s16x8*)(L + o);
            s16x8 alv = *(const s16x8*)(L + 4096 + o);
            #pragma unroll
            for (int nf = 0; nf < 4; ++nf) {
                acc[mf][nf] = __builtin_amdgcn_mfma_f32_16x16x32_bf16(ahv, bh[nf], acc[mf][nf], 0, 0, 0);
                acc[mf][nf] = __builtin_amdgcn_mfma_f32_16x16x32_bf16(ahv, bl[nf], acc[mf][nf], 0, 0, 0);
                acc[mf][nf] = __builtin_amdgcn_mfma_f32_16x16x32_bf16(alv, bh[nf], acc[mf][nf], 0, 0, 0);
            }
        }
        cur ^= 1;
    }

    #pragma unroll
    for (int mf = 0; mf < 4; ++mf) {
        const int row0 = bm0 + wr * 64 + mf * 16 + (lane >> 4) * 4;
        #pragma unroll
        for (int nf = 0; nf < 4; ++nf) {
            const int col = bn0 + wc * 64 + nf * 16 + (lane & 15);
            #pragma unroll
            for (int r = 0; r < 4; ++r) {
                if (row0 + r < M)
                    C[(size_t)(row0 + r) * ldc + col] = acc[mf][nf][r];
            }
        }
    }
}

// ---------------------------------------------------------------------------
// f32 -> hi/lo bf16 split kernels
// ---------------------------------------------------------------------------
__global__ __launch_bounds__(256)
void split_kernel(const float* __restrict__ A, u16* __restrict__ Hh,
                  u16* __restrict__ Hl, int M, int kshift)
{
    const size_t g  = (size_t)blockIdx.x * 256 + threadIdx.x;
    const size_t i4 = g * 4;
    const int row   = (int)(i4 >> kshift);
    f32x4 v = {0.f, 0.f, 0.f, 0.f};
    if (row < M) v = *(const f32x4*)(A + i4);
    u16x4 h, l;
    #pragma unroll
    for (int j = 0; j < 4; ++j) {
        u16 hb = f2bf(v[j]);
        h[j] = hb;
        l[j] = f2bf(v[j] - bf2f(hb));
    }
    *(u16x4*)(Hh + i4) = h;
    *(u16x4*)(Hl + i4) = l;
}

__global__ __launch_bounds__(256)
void relu_split_kernel(const float* __restrict__ Y, int ld, int coff,
                       u16* __restrict__ Hh, u16* __restrict__ Hl, int M)
{
    const size_t g  = (size_t)blockIdx.x * 256 + threadIdx.x;
    const size_t i4 = g * 4;
    const int row   = (int)(i4 >> 9);
    const int col   = (int)(i4 & 511);
    f32x4 v = {0.f, 0.f, 0.f, 0.f};
    if (row < M) v = *(const f32x4*)(Y + (size_t)row * ld + coff + col);
    u16x4 h, l;
    #pragma unroll
    for (int j = 0; j < 4; ++j) {
        float x = fmaxf(v[j], 0.f);
        u16 hb = f2bf(x);
        h[j] = hb;
        l[j] = f2bf(x - bf2f(hb));
    }
    *(u16x4*)(Hh + i4) = h;
    *(u16x4*)(Hl + i4) = l;
}

// ---------------------------------------------------------------------------
// CSR build: zero -> histogram -> block scan -> aux scan -> finalize -> fill
// ---------------------------------------------------------------------------
__global__ __launch_bounds__(256)
void zero_i32_kernel(int* __restrict__ p, int n)
{
    int i = blockIdx.x * 256 + threadIdx.x;
    if (i < n) p[i] = 0;
}

// grid (ceil(E/256), S)
__global__ __launch_bounds__(256)
void hist_kernel(const int* __restrict__ rows, int* __restrict__ counts,
                 int N, int E)
{
    int s = blockIdx.y;
    int e = blockIdx.x * 256 + threadIdx.x;
    if (e < E) atomicAdd(counts + s * N + rows[(size_t)s * E + e], 1);
}

// grid (NB, S): per-block exclusive scan of counts -> rowptr, block sums out
__global__ __launch_bounds__(256)
void scan_block_kernel(const int* __restrict__ counts, int* __restrict__ rowptr,
                       int* __restrict__ blocksum, int N, int np1, int NB)
{
    __shared__ int sd[256];
    int s = blockIdx.y;
    int i = blockIdx.x * 256 + threadIdx.x;
    int tid = threadIdx.x;
    int v = (i < N) ? counts[s * N + i] : 0;
    sd[tid] = v;
    __syncthreads();
    #pragma unroll
    for (int off = 1; off < 256; off <<= 1) {
        int t = (tid >= off) ? sd[tid - off] : 0;
        __syncthreads();
        sd[tid] += t;
        __syncthreads();
    }
    if (i < N) rowptr[s * np1 + i] = sd[tid] - v;   // exclusive within block
    if (tid == 255) blocksum[s * NB + blockIdx.x] = sd[255];
}

// grid (S), block 256; NB <= 256: exclusive scan of blocksum in place
__global__ __launch_bounds__(256)
void scan_aux_kernel(int* __restrict__ blocksum, int NB)
{
    __shared__ int sd[256];
    int s = blockIdx.x;
    int tid = threadIdx.x;
    int v = (tid < NB) ? blocksum[s * NB + tid] : 0;
    sd[tid] = v;
    __syncthreads();
    #pragma unroll
    for (int off = 1; off < 256; off <<= 1) {
        int t = (tid >= off) ? sd[tid - off] : 0;
        __syncthreads();
        sd[tid] += t;
        __syncthreads();
    }
    if (tid < NB) blocksum[s * NB + tid] = sd[tid] - v;
}

// grid (NB, S): rowptr += block offset; init cursor; set rowptr[N] = E
__global__ __launch_bounds__(256)
void finalize_rowptr_kernel(int* __restrict__ rowptr, const int* __restrict__ blocksum,
                            int* __restrict__ cursor, int N, int np1, int NB, int E)
{
    int s = blockIdx.y;
    int i = blockIdx.x * 256 + threadIdx.x;
    if (i < N) {
        int v = rowptr[s * np1 + i] + blocksum[s * NB + blockIdx.x];
        rowptr[s * np1 + i] = v;
        cursor[s * N + i] = v;
    }
    if (i == N) rowptr[s * np1 + N] = E;
}

// grid (ceil(E/256), S)
__global__ __launch_bounds__(256)
void fill_csr_kernel(const int* __restrict__ rows, const int* __restrict__ cols,
                     const float* __restrict__ vals, int* __restrict__ cursor,
                     int* __restrict__ colsrt, float* __restrict__ valsrt,
                     int N, int E)
{
    int s = blockIdx.y;
    int e = blockIdx.x * 256 + threadIdx.x;
    if (e < E) {
        size_t idx = (size_t)s * E + e;
        int r = rows[idx];
        int pos = atomicAdd(cursor + s * N + r, 1);
        colsrt[(size_t)s * E + pos] = cols[idx];
        valsrt[(size_t)s * E + pos] = vals[idx];
    }
}

// ---------------------------------------------------------------------------
// CSR SpMM: grid (N_out), block 256 = 4 waves, wave s handles relation s.
// Out[r, ocol + s*KCH + ch] += sum_e v_e * In[c_e, s*KCH + ch]
// ---------------------------------------------------------------------------
template<int KCH>
__global__ __launch_bounds__(256)
void spmm_csr_kernel(const int* __restrict__ rowptr, int np1,
                     const int* __restrict__ colsrt, const float* __restrict__ valsrt,
                     const float* __restrict__ In, int ldi,
                     float* __restrict__ Out, int ldo, int ocol, int E)
{
    const int r    = blockIdx.x;
    const int s    = threadIdx.x >> 6;
    const int lane = threadIdx.x & 63;
    int e0 = rowptr[s * np1 + r];
    int e1 = rowptr[s * np1 + r + 1];
    if (e0 == e1) return;   // wave-uniform
    const int* cs  = colsrt + (size_t)s * E;
    const float* vs = valsrt + (size_t)s * E;

    if (KCH == 128) {
        const int col = s * 128 + lane * 2;
        float ax = 0.f, ay = 0.f;
        int e = e0;
        for (; e + 1 < e1; e += 2) {
            int   ca = cs[e],     cb = cs[e + 1];
            float va = vs[e],     vb = vs[e + 1];
            float2 xa = *(const float2*)(In + (size_t)ca * ldi + col);
            float2 xb = *(const float2*)(In + (size_t)cb * ldi + col);
            ax += va * xa.x + vb * xb.x;
            ay += va * xa.y + vb * xb.y;
        }
        if (e < e1) {
            int c = cs[e]; float v = vs[e];
            float2 x = *(const float2*)(In + (size_t)c * ldi + col);
            ax += v * x.x;
            ay += v * x.y;
        }
        float2* o = (float2*)(Out + (size_t)r * ldo + ocol + col);
        float2 cval = *o;
        cval.x += ax; cval.y += ay;
        *o = cval;
    } else {
        const int col = s * 64 + lane;
        float acc = 0.f;
        int e = e0;
        for (; e + 1 < e1; e += 2) {
            int   ca = cs[e],     cb = cs[e + 1];
            float va = vs[e],     vb = vs[e + 1];
            acc += va * In[(size_t)ca * ldi + col] + vb * In[(size_t)cb * ldi + col];
        }
        if (e < e1)
            acc += vs[e] * In[(size_t)cs[e] * ldi + col];
        Out[(size_t)r * ldo + ocol + col] += acc;
    }
}

template<int NC>
__global__ __launch_bounds__(256)
void relu_out_kernel(const float* __restrict__ Z, int ld, int coff,
                     float* __restrict__ out, int M)
{
    int g = blockIdx.x * 256 + threadIdx.x;
    if (g >= M * NC) return;
    int row = g / NC;
    int col = g & (NC - 1);
    float x = Z[(size_t)row * ld + coff + col];
    out[g] = fmaxf(x, 0.f);
}

// ---------------------------------------------------------------------------
// weight packing (transposed [N][K], hi/lo)
// ---------------------------------------------------------------------------
__global__ __launch_bounds__(256)
void pack_b0_split_kernel(const float* __restrict__ w0, const float* __restrict__ sw0,
                          u16* __restrict__ Bh, u16* __restrict__ Bl)
{
    int g = blockIdx.x * 256 + threadIdx.x;
    int j = g >> 10, d = g & 1023;
    float v;
    if (j < 512) v = w0[((size_t)(j >> 7) * 1024 + d) * 128 + (j & 127)];
    else         v = sw0[(size_t)d * 512 + (j - 512)];
    u16 h = f2bf(v);
    Bh[g] = h;
    Bl[g] = f2bf(v - bf2f(h));
}

__global__ __launch_bounds__(256)
void pack_b1_split_kernel(const float* __restrict__ w1, const float* __restrict__ sw1,
                          u16* __restrict__ Bh, u16* __restrict__ Bl)
{
    int g = blockIdx.x * 256 + threadIdx.x;
    int j = g >> 9, d = g & 511;
    float v;
    if (j < 256) v = w1[((size_t)(j >> 6) * 512 + d) * 64 + (j & 63)];
    else         v = sw1[(size_t)d * 256 + (j - 256)];
    u16 h = f2bf(v);
    Bh[g] = h;
    Bl[g] = f2bf(v - bf2f(h));
}

extern "C" void kernel_launch(void* const* d_in, const int* in_sizes, int n_in,
                              void* d_out, int out_size, void* d_ws, size_t ws_size,
                              hipStream_t stream)
{
    const int*   rna_rows  = (const int*)  d_in[0];
    const int*   rna_cols  = (const int*)  d_in[1];
    const float* rna_vals  = (const float*)d_in[2];
    const int*   prot_rows = (const int*)  d_in[3];
    const int*   prot_cols = (const int*)  d_in[4];
    const float* prot_vals = (const float*)d_in[5];
    const float* H_rna     = (const float*)d_in[6];
    const float* H_prot    = (const float*)d_in[7];
    const float* w0        = (const float*)d_in[8];
    const float* sw0       = (const float*)d_in[9];
    const float* w1        = (const float*)d_in[10];
    const float* sw1       = (const float*)d_in[11];

    const int NRNA = 50000, NPROT = 20000, S = 4, E = 500000;
    const int MP_RNA = 50048, MP_PROT = 20096;
    const int NP1_R = NRNA + 1, NP1_P = NPROT + 1;
    const int NB_R = (NRNA + 255) / 256;    // 196
    const int NB_P = (NPROT + 255) / 256;   // 79
    const int EB   = (E + 255) / 256;       // 1954

    // --- workspace layout (497 MB, same as round 2) ---
    float* Yrna  = (float*)d_ws;
    float* Yprot = Yrna  + (size_t)NRNA  * 1024;
    u16*   Ah    = (u16*)(Yprot + (size_t)NPROT * 1024);
    u16*   Al    = Ah  + (size_t)MP_RNA * 1024;
    u16*   B0h   = Al  + (size_t)MP_RNA * 1024;
    u16*   B0l   = B0h + 1024 * 1024;
    u16*   B1h   = B0l + 1024 * 1024;
    u16*   B1l   = B1h + 512 * 512;

    // --- CSR scratch lives in d_out (dead until final relu) ---
    int*   colsrtR = (int*)d_out;                       // S*E
    float* valsrtR = (float*)(colsrtR + (size_t)S * E); // S*E
    int*   colsrtP = (int*)(valsrtR + (size_t)S * E);
    float* valsrtP = (float*)(colsrtP + (size_t)S * E);
    int*   countsR = (int*)(valsrtP + (size_t)S * E);   // S*NRNA
    int*   rowptrR = countsR + (size_t)S * NRNA;        // S*NP1_R
    int*   cursorR = rowptrR + (size_t)S * NP1_R;       // S*NRNA
    int*   bsumR   = cursorR + (size_t)S * NRNA;        // S*NB_R
    int*   countsP = bsumR   + (size_t)S * NB_R;
    int*   rowptrP = countsP + (size_t)S * NPROT;
    int*   cursorP = rowptrP + (size_t)S * NP1_P;
    int*   bsumP   = cursorP + (size_t)S * NPROT;

    dim3 blk(256);

    // --- pack weights ---
    pack_b0_split_kernel<<<(1024 * 1024) / 256, blk, 0, stream>>>(w0, sw0, B0h, B0l);
    pack_b1_split_kernel<<<(512 * 512) / 256, blk, 0, stream>>>(w1, sw1, B1h, B1l);

    // --- CSR build (both sides, once; reused by both layers) ---
    zero_i32_kernel<<<(S * NRNA + 255) / 256, blk, 0, stream>>>(countsR, S * NRNA);
    zero_i32_kernel<<<(S * NPROT + 255) / 256, blk, 0, stream>>>(countsP, S * NPROT);
    hist_kernel<<<dim3(EB, S), blk, 0, stream>>>(rna_rows, countsR, NRNA, E);
    hist_kernel<<<dim3(EB, S), blk, 0, stream>>>(prot_rows, countsP, NPROT, E);
    scan_block_kernel<<<dim3(NB_R, S), blk, 0, stream>>>(countsR, rowptrR, bsumR, NRNA, NP1_R, NB_R);
    scan_block_kernel<<<dim3(NB_P, S), blk, 0, stream>>>(countsP, rowptrP, bsumP, NPROT, NP1_P, NB_P);
    scan_aux_kernel<<<S, blk, 0, stream>>>(bsumR, NB_R);
    scan_aux_kernel<<<S, blk, 0, stream>>>(bsumP, NB_P);
    finalize_rowptr_kernel<<<dim3(NB_R, S), blk, 0, stream>>>(rowptrR, bsumR, cursorR, NRNA, NP1_R, NB_R, E);
    finalize_rowptr_kernel<<<dim3(NB_P, S), blk, 0, stream>>>(rowptrP, bsumP, cursorP, NPROT, NP1_P, NB_P, E);
    fill_csr_kernel<<<dim3(EB, S), blk, 0, stream>>>(rna_rows, rna_cols, rna_vals,
                                                     cursorR, colsrtR, valsrtR, NRNA, E);
    fill_csr_kernel<<<dim3(EB, S), blk, 0, stream>>>(prot_rows, prot_cols, prot_vals,
                                                     cursorP, colsrtP, valsrtP, NPROT, E);

    // --- layer 0: split + GEMM (N=K=1024) ---
    split_kernel<<<MP_RNA, blk, 0, stream>>>(H_rna, Ah, Al, NRNA, 10);
    {
        dim3 grid(1024 / 128, MP_RNA / 128);
        gemm_split_kernel<<<grid, blk, 0, stream>>>(Ah, Al, B0h, B0l, Yrna, 1024, NRNA, 1024);
    }
    split_kernel<<<MP_PROT, blk, 0, stream>>>(H_prot, Ah, Al, NPROT, 10);
    {
        dim3 grid(1024 / 128, MP_PROT / 128);
        gemm_split_kernel<<<grid, blk, 0, stream>>>(Ah, Al, B0h, B0l, Yprot, 1024, NPROT, 1024);
    }
    // --- layer 0 SpMM: base(cols 512..1023) += agg(tmp_other cols 0..511) ---
    spmm_csr_kernel<128><<<NRNA, blk, 0, stream>>>(rowptrR, NP1_R, colsrtR, valsrtR,
                                                   Yprot, 1024, Yrna, 1024, 512, E);
    spmm_csr_kernel<128><<<NPROT, blk, 0, stream>>>(rowptrP, NP1_P, colsrtP, valsrtP,
                                                    Yrna, 1024, Yprot, 1024, 512, E);

    // --- layer 1: relu+split + GEMM (N=K=512, C -> Y cols 0..511) ---
    relu_split_kernel<<<MP_RNA / 2, blk, 0, stream>>>(Yrna, 1024, 512, Ah, Al, NRNA);
    {
        dim3 grid(512 / 128, MP_RNA / 128);
        gemm_split_kernel<<<grid, blk, 0, stream>>>(Ah, Al, B1h, B1l, Yrna, 1024, NRNA, 512);
    }
    relu_split_kernel<<<MP_PROT / 2, blk, 0, stream>>>(Yprot, 1024, 512, Ah, Al, NPROT);
    {
        dim3 grid(512 / 128, MP_PROT / 128);
        gemm_split_kernel<<<grid, blk, 0, stream>>>(Ah, Al, B1h, B1l, Yprot, 1024, NPROT, 512);
    }
    // --- layer 1 SpMM (KCH=64, base at cols 256..511, tmp at cols 0..255) ---
    spmm_csr_kernel<64><<<NRNA, blk, 0, stream>>>(rowptrR, NP1_R, colsrtR, valsrtR,
                                                  Yprot, 1024, Yrna, 1024, 256, E);
    spmm_csr_kernel<64><<<NPROT, blk, 0, stream>>>(rowptrP, NP1_P, colsrtP, valsrtP,
                                                   Yrna, 1024, Yprot, 1024, 256, E);

    // --- final relu -> d_out (overwrites CSR scratch; CSR is dead now) ---
    float* out = (float*)d_out;
    relu_out_kernel<256><<<(NRNA * 256) / 256, blk, 0, stream>>>(Yrna, 1024, 256, out, NRNA);
    relu_out_kernel<256><<<(NPROT * 256) / 256, blk, 0, stream>>>(Yprot, 1024, 256,
                                                                  out + (size_t)NRNA * 256, NPROT);
}

// Round 4
// 1634.015 us; speedup vs baseline: 3.0745x; 1.1229x over previous
//
#include <hip/hip_runtime.h>
#include <hip/hip_bf16.h>

// ---------------------------------------------------------------------------
// StackGCNEncoder on MI355X — round 4:
//   + XCD-swizzled GEMM grid (A-panel fetched once per XCD)
//   + relu/split fused into spmm epilogues (L0 -> bf16 A-operands, L1 -> d_out)
//   + unroll-4 spmm gather
// CSR scratch moves to ws tail when ws_size allows (fallback: d_out + unfused
// L1 spmm + relu_out, as round 3).
// ---------------------------------------------------------------------------

typedef unsigned short u16;
typedef short s16x8 __attribute__((ext_vector_type(8)));
typedef float f32x4 __attribute__((ext_vector_type(4)));
typedef __attribute__((ext_vector_type(4))) unsigned short u16x4;
typedef __attribute__((ext_vector_type(2))) unsigned short u16x2;

__device__ __forceinline__ u16 f2bf(float x) {            // RNE f32->bf16
    unsigned u = __float_as_uint(x);
    return (u16)((u + 0x7fff + ((u >> 16) & 1)) >> 16);
}
__device__ __forceinline__ float bf2f(u16 h) {
    return __uint_as_float(((unsigned)h) << 16);
}

__device__ __forceinline__ void gload16(const u16* g, u16* l) {
    __builtin_amdgcn_global_load_lds(
        (const __attribute__((address_space(1))) unsigned int*)g,
        (__attribute__((address_space(3))) unsigned int*)l,
        16, 0, 0);
}

// ---------------------------------------------------------------------------
// Split-bf16 GEMM: C[M][N] = A[Mpad][K] x B^T[N][K]. 128x128 tile, BK=32.
// 1-D grid, bijective XCD swizzle; bx = N-block (fastest), NXB = 1<<nxshift.
// ---------------------------------------------------------------------------
__global__ __launch_bounds__(256)
void gemm_split_kernel(const u16* __restrict__ Ah, const u16* __restrict__ Al,
                       const u16* __restrict__ Bh, const u16* __restrict__ Bl,
                       float* __restrict__ C, int ldc,
                       int M, int K, int nxmask, int nxshift)
{
    __shared__ u16 lds[2][4][128 * 32];   // 64 KB

    // bijective XCD swizzle (m204 variant): consecutive lin ids -> same XCD
    const int nwg = gridDim.x;
    const int q   = nwg >> 3, r8 = nwg & 7;
    const int xcd = blockIdx.x & 7, pos = blockIdx.x >> 3;
    const int lin = (xcd < r8 ? xcd * (q + 1) : r8 * (q + 1) + (xcd - r8) * q) + pos;
    const int bm0 = (lin >> nxshift) * 128;
    const int bn0 = (lin & nxmask) * 128;

    const int tid  = threadIdx.x;
    const int lane = tid & 63;
    const int wid  = tid >> 6;
    const int wr   = wid >> 1;
    const int wc   = wid & 1;

    const int srow = tid >> 2;
    const int scol = (tid & 3) * 8;
    const size_t aoff0 = (size_t)(bm0 + srow) * K + scol;
    const size_t aoff1 = (size_t)(bm0 + srow + 64) * K + scol;
    const size_t boff0 = (size_t)(bn0 + srow) * K + scol;
    const size_t boff1 = (size_t)(bn0 + srow + 64) * K + scol;
    const int c0 = tid * 8;
    const int c1 = 2048 + tid * 8;

    u16* L0 = &lds[0][0][0];

    f32x4 zero = {0.f, 0.f, 0.f, 0.f};
    f32x4 acc[4][4];
    #pragma unroll
    for (int i = 0; i < 4; ++i)
        #pragma unroll
        for (int j = 0; j < 4; ++j) acc[i][j] = zero;

    const int a_fr = (wr * 64 + (lane & 15)) * 32 + (lane >> 4) * 8;
    const int b_fr = (wc * 64 + (lane & 15)) * 32 + (lane >> 4) * 8;

    const int nk = K >> 5;

    {
        u16* L = L0;
        gload16(Ah + aoff0, L + c0);            gload16(Ah + aoff1, L + c1);
        gload16(Al + aoff0, L + 4096 + c0);     gload16(Al + aoff1, L + 4096 + c1);
        gload16(Bh + boff0, L + 8192 + c0);     gload16(Bh + boff1, L + 8192 + c1);
        gload16(Bl + boff0, L + 12288 + c0);    gload16(Bl + boff1, L + 12288 + c1);
    }

    int cur = 0;
    for (int t = 0; t < nk; ++t) {
        __syncthreads();
        if (t + 1 < nk) {
            const int k0 = (t + 1) * 32;
            u16* L = L0 + (cur ^ 1) * 16384;
            gload16(Ah + aoff0 + k0, L + c0);         gload16(Ah + aoff1 + k0, L + c1);
            gload16(Al + aoff0 + k0, L + 4096 + c0);  gload16(Al + aoff1 + k0, L + 4096 + c1);
            gload16(Bh + boff0 + k0, L + 8192 + c0);  gload16(Bh + boff1 + k0, L + 8192 + c1);
            gload16(Bl + boff0 + k0, L + 12288 + c0); gload16(Bl + boff1 + k0, L + 12288 + c1);
        }
        const u16* L = L0 + cur * 16384;
        s16x8 bh[4], bl[4];
        #pragma unroll
        for (int nf = 0; nf < 4; ++nf) {
            const int o = b_fr + nf * 512;
            bh[nf] = *(const s16x8*)(L + 8192 + o);
            bl[nf] = *(const s16x8*)(L + 12288 + o);
        }
        #pragma unroll
        for (int mf = 0; mf < 4; ++mf) {
            const int o = a_fr + mf * 512;
            s16x8 ahv = *(const s16x8*)(L + o);
            s16x8 alv = *(const s16x8*)(L + 4096 + o);
            #pragma unroll
            for (int nf = 0; nf < 4; ++nf) {
                acc[mf][nf] = __builtin_amdgcn_mfma_f32_16x16x32_bf16(ahv, bh[nf], acc[mf][nf], 0, 0, 0);
                acc[mf][nf] = __builtin_amdgcn_mfma_f32_16x16x32_bf16(ahv, bl[nf], acc[mf][nf], 0, 0, 0);
                acc[mf][nf] = __builtin_amdgcn_mfma_f32_16x16x32_bf16(alv, bh[nf], acc[mf][nf], 0, 0, 0);
            }
        }
        cur ^= 1;
    }

    #pragma unroll
    for (int mf = 0; mf < 4; ++mf) {
        const int row0 = bm0 + wr * 64 + mf * 16 + (lane >> 4) * 4;
        #pragma unroll
        for (int nf = 0; nf < 4; ++nf) {
            const int col = bn0 + wc * 64 + nf * 16 + (lane & 15);
            #pragma unroll
            for (int r = 0; r < 4; ++r) {
                if (row0 + r < M)
                    C[(size_t)(row0 + r) * ldc + col] = acc[mf][nf][r];
            }
        }
    }
}

// ---------------------------------------------------------------------------
// f32 [M][K] -> hi/lo bf16 [Mpad][K], zero-padded rows. 4 elems/thread.
// ---------------------------------------------------------------------------
__global__ __launch_bounds__(256)
void split_kernel(const float* __restrict__ A, u16* __restrict__ Hh,
                  u16* __restrict__ Hl, int M, int kshift)
{
    const size_t g  = (size_t)blockIdx.x * 256 + threadIdx.x;
    const size_t i4 = g * 4;
    const int row   = (int)(i4 >> kshift);
    f32x4 v = {0.f, 0.f, 0.f, 0.f};
    if (row < M) v = *(const f32x4*)(A + i4);
    u16x4 h, l;
    #pragma unroll
    for (int j = 0; j < 4; ++j) {
        u16 hb = f2bf(v[j]);
        h[j] = hb;
        l[j] = f2bf(v[j] - bf2f(hb));
    }
    *(u16x4*)(Hh + i4) = h;
    *(u16x4*)(Hl + i4) = l;
}

__global__ __launch_bounds__(256)
void zero_u16_kernel(u16* __restrict__ p, int n)
{
    int i = blockIdx.x * 256 + threadIdx.x;
    if (i < n) p[i] = 0;
}

// ---------------------------------------------------------------------------
// CSR build: zero -> histogram -> block scan -> aux scan -> finalize -> fill
// ---------------------------------------------------------------------------
__global__ __launch_bounds__(256)
void zero_i32_kernel(int* __restrict__ p, int n)
{
    int i = blockIdx.x * 256 + threadIdx.x;
    if (i < n) p[i] = 0;
}

__global__ __launch_bounds__(256)
void hist_kernel(const int* __restrict__ rows, int* __restrict__ counts,
                 int N, int E)
{
    int s = blockIdx.y;
    int e = blockIdx.x * 256 + threadIdx.x;
    if (e < E) atomicAdd(counts + s * N + rows[(size_t)s * E + e], 1);
}

__global__ __launch_bounds__(256)
void scan_block_kernel(const int* __restrict__ counts, int* __restrict__ rowptr,
                       int* __restrict__ blocksum, int N, int np1, int NB)
{
    __shared__ int sd[256];
    int s = blockIdx.y;
    int i = blockIdx.x * 256 + threadIdx.x;
    int tid = threadIdx.x;
    int v = (i < N) ? counts[s * N + i] : 0;
    sd[tid] = v;
    __syncthreads();
    #pragma unroll
    for (int off = 1; off < 256; off <<= 1) {
        int t = (tid >= off) ? sd[tid - off] : 0;
        __syncthreads();
        sd[tid] += t;
        __syncthreads();
    }
    if (i < N) rowptr[s * np1 + i] = sd[tid] - v;
    if (tid == 255) blocksum[s * NB + blockIdx.x] = sd[255];
}

__global__ __launch_bounds__(256)
void scan_aux_kernel(int* __restrict__ blocksum, int NB)
{
    __shared__ int sd[256];
    int s = blockIdx.x;
    int tid = threadIdx.x;
    int v = (tid < NB) ? blocksum[s * NB + tid] : 0;
    sd[tid] = v;
    __syncthreads();
    #pragma unroll
    for (int off = 1; off < 256; off <<= 1) {
        int t = (tid >= off) ? sd[tid - off] : 0;
        __syncthreads();
        sd[tid] += t;
        __syncthreads();
    }
    if (tid < NB) blocksum[s * NB + tid] = sd[tid] - v;
}

__global__ __launch_bounds__(256)
void finalize_rowptr_kernel(int* __restrict__ rowptr, const int* __restrict__ blocksum,
                            int* __restrict__ cursor, int N, int np1, int NB, int E)
{
    int s = blockIdx.y;
    int i = blockIdx.x * 256 + threadIdx.x;
    if (i < N) {
        int v = rowptr[s * np1 + i] + blocksum[s * NB + blockIdx.x];
        rowptr[s * np1 + i] = v;
        cursor[s * N + i] = v;
    }
    if (i == N) rowptr[s * np1 + N] = E;
}

__global__ __launch_bounds__(256)
void fill_csr_kernel(const int* __restrict__ rows, const int* __restrict__ cols,
                     const float* __restrict__ vals, int* __restrict__ cursor,
                     int* __restrict__ colsrt, float* __restrict__ valsrt,
                     int N, int E)
{
    int s = blockIdx.y;
    int e = blockIdx.x * 256 + threadIdx.x;
    if (e < E) {
        size_t idx = (size_t)s * E + e;
        int r = rows[idx];
        int pos = atomicAdd(cursor + s * N + r, 1);
        colsrt[(size_t)s * E + pos] = cols[idx];
        valsrt[(size_t)s * E + pos] = vals[idx];
    }
}

// ---------------------------------------------------------------------------
// CSR SpMM: grid (N_out), 4 waves = 4 relations, unroll-4 gather.
// MODE 0: Base[r][bcol+col] += acc                       (unfused, fallback L1)
// MODE 1: OutH/OutL[r][col]  = split(relu(Base+acc))     (L0 -> layer-1 A)
// MODE 2: OutF[r][col]       = relu(Base+acc)            (L1 -> d_out)
// ---------------------------------------------------------------------------
template<int KCH, int MODE>
__global__ __launch_bounds__(256)
void spmm_csr_kernel(const int* __restrict__ rowptr, int np1,
                     const int* __restrict__ colsrt, const float* __restrict__ valsrt,
                     const float* __restrict__ In, int ldi,
                     float* __restrict__ Base, int ldb, int bcol,
                     u16* __restrict__ OutH, u16* __restrict__ OutL,
                     float* __restrict__ OutF, int ldo, int E)
{
    const int r    = blockIdx.x;
    const int s    = threadIdx.x >> 6;
    const int lane = threadIdx.x & 63;
    int e0 = rowptr[s * np1 + r];
    int e1 = rowptr[s * np1 + r + 1];
    if (MODE == 0 && e0 == e1) return;   // wave-uniform
    const int* cs   = colsrt + (size_t)s * E;
    const float* vs = valsrt + (size_t)s * E;

    if (KCH == 128) {
        const int col = s * 128 + lane * 2;
        float ax = 0.f, ay = 0.f;
        int e = e0;
        for (; e + 3 < e1; e += 4) {
            int   ca = cs[e],   cb = cs[e+1], cc = cs[e+2], cd = cs[e+3];
            float va = vs[e],   vb = vs[e+1], vc = vs[e+2], vd = vs[e+3];
            float2 xa = *(const float2*)(In + (size_t)ca * ldi + col);
            float2 xb = *(const float2*)(In + (size_t)cb * ldi + col);
            float2 xc = *(const float2*)(In + (size_t)cc * ldi + col);
            float2 xd = *(const float2*)(In + (size_t)cd * ldi + col);
            ax += va * xa.x + vb * xb.x + vc * xc.x + vd * xd.x;
            ay += va * xa.y + vb * xb.y + vc * xc.y + vd * xd.y;
        }
        for (; e < e1; ++e) {
            int c = cs[e]; float v = vs[e];
            float2 x = *(const float2*)(In + (size_t)c * ldi + col);
            ax += v * x.x;  ay += v * x.y;
        }
        if (MODE == 0) {
            float2* o = (float2*)(Base + (size_t)r * ldb + bcol + col);
            float2 cv = *o; cv.x += ax; cv.y += ay; *o = cv;
        } else {
            const float2 b = *(const float2*)(Base + (size_t)r * ldb + bcol + col);
            float fx = fmaxf(b.x + ax, 0.f), fy = fmaxf(b.y + ay, 0.f);
            u16 hx = f2bf(fx), hy = f2bf(fy);
            u16x2 h = {hx, hy};
            u16x2 l = {f2bf(fx - bf2f(hx)), f2bf(fy - bf2f(hy))};
            *(u16x2*)(OutH + (size_t)r * ldo + col) = h;
            *(u16x2*)(OutL + (size_t)r * ldo + col) = l;
        }
    } else {   // KCH == 64
        const int col = s * 64 + lane;
        float acc = 0.f;
        int e = e0;
        for (; e + 3 < e1; e += 4) {
            int   ca = cs[e],   cb = cs[e+1], cc = cs[e+2], cd = cs[e+3];
            float va = vs[e],   vb = vs[e+1], vc = vs[e+2], vd = vs[e+3];
            acc += va * In[(size_t)ca * ldi + col] + vb * In[(size_t)cb * ldi + col]
                 + vc * In[(size_t)cc * ldi + col] + vd * In[(size_t)cd * ldi + col];
        }
        for (; e < e1; ++e)
            acc += vs[e] * In[(size_t)cs[e] * ldi + col];
        if (MODE == 0) {
            Base[(size_t)r * ldb + bcol + col] += acc;
        } else {
            OutF[(size_t)r * ldo + col] = fmaxf(Base[(size_t)r * ldb + bcol + col] + acc, 0.f);
        }
    }
}

// fallback-only final relu
template<int NC>
__global__ __launch_bounds__(256)
void relu_out_kernel(const float* __restrict__ Z, int ld, int coff,
                     float* __restrict__ out, int M)
{
    int g = blockIdx.x * 256 + threadIdx.x;
    if (g >= M * NC) return;
    int row = g / NC;
    int col = g & (NC - 1);
    out[g] = fmaxf(Z[(size_t)row * ld + coff + col], 0.f);
}

// ---------------------------------------------------------------------------
// weight packing (transposed [N][K], hi/lo)
// ---------------------------------------------------------------------------
__global__ __launch_bounds__(256)
void pack_b0_split_kernel(const float* __restrict__ w0, const float* __restrict__ sw0,
                          u16* __restrict__ Bh, u16* __restrict__ Bl)
{
    int g = blockIdx.x * 256 + threadIdx.x;
    int j = g >> 10, d = g & 1023;
    float v;
    if (j < 512) v = w0[((size_t)(j >> 7) * 1024 + d) * 128 + (j & 127)];
    else         v = sw0[(size_t)d * 512 + (j - 512)];
    u16 h = f2bf(v);
    Bh[g] = h;
    Bl[g] = f2bf(v - bf2f(h));
}

__global__ __launch_bounds__(256)
void pack_b1_split_kernel(const float* __restrict__ w1, const float* __restrict__ sw1,
                          u16* __restrict__ Bh, u16* __restrict__ Bl)
{
    int g = blockIdx.x * 256 + threadIdx.x;
    int j = g >> 9, d = g & 511;
    float v;
    if (j < 256) v = w1[((size_t)(j >> 6) * 512 + d) * 64 + (j & 63)];
    else         v = sw1[(size_t)d * 256 + (j - 256)];
    u16 h = f2bf(v);
    Bh[g] = h;
    Bl[g] = f2bf(v - bf2f(h));
}

extern "C" void kernel_launch(void* const* d_in, const int* in_sizes, int n_in,
                              void* d_out, int out_size, void* d_ws, size_t ws_size,
                              hipStream_t stream)
{
    const int*   rna_rows  = (const int*)  d_in[0];
    const int*   rna_cols  = (const int*)  d_in[1];
    const float* rna_vals  = (const float*)d_in[2];
    const int*   prot_rows = (const int*)  d_in[3];
    const int*   prot_cols = (const int*)  d_in[4];
    const float* prot_vals = (const float*)d_in[5];
    const float* H_rna     = (const float*)d_in[6];
    const float* H_prot    = (const float*)d_in[7];
    const float* w0        = (const float*)d_in[8];
    const float* sw0       = (const float*)d_in[9];
    const float* w1        = (const float*)d_in[10];
    const float* sw1       = (const float*)d_in[11];

    const int NRNA = 50000, NPROT = 20000, S = 4, E = 500000;
    const int MP_RNA = 50048, MP_PROT = 20096;
    const int NP1_R = NRNA + 1, NP1_P = NPROT + 1;
    const int NB_R = (NRNA + 255) / 256;
    const int NB_P = (NPROT + 255) / 256;
    const int EB   = (E + 255) / 256;

    // --- ws layout ---
    char* ws = (char*)d_ws;
    size_t off = 0;
    float* Yrna  = (float*)(ws + off); off += (size_t)NRNA  * 1024 * 4;
    float* Yprot = (float*)(ws + off); off += (size_t)NPROT * 1024 * 4;
    u16*   Ahbig = (u16*)  (ws + off); off += (size_t)MP_RNA * 1024 * 2;
    u16*   Albig = (u16*)  (ws + off); off += (size_t)MP_RNA * 1024 * 2;
    u16*   B0h   = (u16*)  (ws + off); off += (size_t)1024 * 1024 * 2;
    u16*   B0l   = (u16*)  (ws + off); off += (size_t)1024 * 1024 * 2;
    u16*   B1h   = (u16*)  (ws + off); off += (size_t)512 * 512 * 2;
    u16*   B1l   = (u16*)  (ws + off); off += (size_t)512 * 512 * 2;
    size_t base_bytes = off;

    // layer-1 A views carved from Ahbig/Albig (disjoint):
    u16* AhR = Ahbig;                           // [MP_RNA][512]
    u16* AlR = Albig;
    u16* AhP = Ahbig + (size_t)MP_RNA * 512;    // [MP_PROT][512]
    u16* AlP = Albig + (size_t)MP_RNA * 512;

    // CSR scratch size
    size_t csr_bytes = 0;
    csr_bytes += (size_t)S * E * 4 * 2 * 2;                 // colsrt/valsrt, both sides
    csr_bytes += ((size_t)S * (NRNA * 2 + NP1_R + NB_R)) * 4;
    csr_bytes += ((size_t)S * (NPROT * 2 + NP1_P + NB_P)) * 4;
    const bool csr_in_ws = (ws_size >= base_bytes + csr_bytes);

    char* csr = csr_in_ws ? (ws + base_bytes) : (char*)d_out;
    size_t coff = 0;
    int*   colsrtR = (int*)  (csr + coff); coff += (size_t)S * E * 4;
    float* valsrtR = (float*)(csr + coff); coff += (size_t)S * E * 4;
    int*   colsrtP = (int*)  (csr + coff); coff += (size_t)S * E * 4;
    float* valsrtP = (float*)(csr + coff); coff += (size_t)S * E * 4;
    int*   countsR = (int*)  (csr + coff); coff += (size_t)S * NRNA * 4;
    int*   rowptrR = (int*)  (csr + coff); coff += (size_t)S * NP1_R * 4;
    int*   cursorR = (int*)  (csr + coff); coff += (size_t)S * NRNA * 4;
    int*   bsumR   = (int*)  (csr + coff); coff += (size_t)S * NB_R * 4;
    int*   countsP = (int*)  (csr + coff); coff += (size_t)S * NPROT * 4;
    int*   rowptrP = (int*)  (csr + coff); coff += (size_t)S * NP1_P * 4;
    int*   cursorP = (int*)  (csr + coff); coff += (size_t)S * NPROT * 4;
    int*   bsumP   = (int*)  (csr + coff); coff += (size_t)S * NB_P * 4;

    dim3 blk(256);
    float* out = (float*)d_out;

    // --- pack weights ---
    pack_b0_split_kernel<<<(1024 * 1024) / 256, blk, 0, stream>>>(w0, sw0, B0h, B0l);
    pack_b1_split_kernel<<<(512 * 512) / 256, blk, 0, stream>>>(w1, sw1, B1h, B1l);

    // --- CSR build (once; reused by both layers) ---
    zero_i32_kernel<<<(S * NRNA + 255) / 256, blk, 0, stream>>>(countsR, S * NRNA);
    zero_i32_kernel<<<(S * NPROT + 255) / 256, blk, 0, stream>>>(countsP, S * NPROT);
    hist_kernel<<<dim3(EB, S), blk, 0, stream>>>(rna_rows, countsR, NRNA, E);
    hist_kernel<<<dim3(EB, S), blk, 0, stream>>>(prot_rows, countsP, NPROT, E);
    scan_block_kernel<<<dim3(NB_R, S), blk, 0, stream>>>(countsR, rowptrR, bsumR, NRNA, NP1_R, NB_R);
    scan_block_kernel<<<dim3(NB_P, S), blk, 0, stream>>>(countsP, rowptrP, bsumP, NPROT, NP1_P, NB_P);
    scan_aux_kernel<<<S, blk, 0, stream>>>(bsumR, NB_R);
    scan_aux_kernel<<<S, blk, 0, stream>>>(bsumP, NB_P);
    finalize_rowptr_kernel<<<dim3(NB_R, S), blk, 0, stream>>>(rowptrR, bsumR, cursorR, NRNA, NP1_R, NB_R, E);
    finalize_rowptr_kernel<<<dim3(NB_P, S), blk, 0, stream>>>(rowptrP, bsumP, cursorP, NPROT, NP1_P, NB_P, E);
    fill_csr_kernel<<<dim3(EB, S), blk, 0, stream>>>(rna_rows, rna_cols, rna_vals,
                                                     cursorR, colsrtR, valsrtR, NRNA, E);
    fill_csr_kernel<<<dim3(EB, S), blk, 0, stream>>>(prot_rows, prot_cols, prot_vals,
                                                     cursorP, colsrtP, valsrtP, NPROT, E);

    // --- layer 0: split + GEMM (N=K=1024, 8 N-blocks) ---
    split_kernel<<<MP_RNA, blk, 0, stream>>>(H_rna, Ahbig, Albig, NRNA, 10);
    gemm_split_kernel<<<8 * (MP_RNA / 128), blk, 0, stream>>>(
        Ahbig, Albig, B0h, B0l, Yrna, 1024, NRNA, 1024, 7, 3);
    split_kernel<<<MP_PROT, blk, 0, stream>>>(H_prot, Ahbig, Albig, NPROT, 10);
    gemm_split_kernel<<<8 * (MP_PROT / 128), blk, 0, stream>>>(
        Ahbig, Albig, B0h, B0l, Yprot, 1024, NPROT, 1024, 7, 3);

    // --- layer 0 SpMM fused: relu+split -> layer-1 A operands (bf16) ---
    spmm_csr_kernel<128, 1><<<NRNA, blk, 0, stream>>>(
        rowptrR, NP1_R, colsrtR, valsrtR, Yprot, 1024,
        Yrna, 1024, 512, AhR, AlR, nullptr, 512, E);
    spmm_csr_kernel<128, 1><<<NPROT, blk, 0, stream>>>(
        rowptrP, NP1_P, colsrtP, valsrtP, Yrna, 1024,
        Yprot, 1024, 512, AhP, AlP, nullptr, 512, E);

    // --- zero layer-1 A pad rows ---
    zero_u16_kernel<<<(48 * 512 + 255) / 256, blk, 0, stream>>>(AhR + (size_t)NRNA * 512, 48 * 512);
    zero_u16_kernel<<<(48 * 512 + 255) / 256, blk, 0, stream>>>(AlR + (size_t)NRNA * 512, 48 * 512);
    zero_u16_kernel<<<(96 * 512 + 255) / 256, blk, 0, stream>>>(AhP + (size_t)NPROT * 512, 96 * 512);
    zero_u16_kernel<<<(96 * 512 + 255) / 256, blk, 0, stream>>>(AlP + (size_t)NPROT * 512, 96 * 512);

    // --- layer 1: GEMM (N=K=512, 4 N-blocks), C -> Y cols 0..511 ---
    gemm_split_kernel<<<4 * (MP_RNA / 128), blk, 0, stream>>>(
        AhR, AlR, B1h, B1l, Yrna, 1024, NRNA, 512, 3, 2);
    gemm_split_kernel<<<4 * (MP_PROT / 128), blk, 0, stream>>>(
        AhP, AlP, B1h, B1l, Yprot, 1024, NPROT, 512, 3, 2);

    // --- layer 1 SpMM ---
    if (csr_in_ws) {
        // fused relu -> d_out directly
        spmm_csr_kernel<64, 2><<<NRNA, blk, 0, stream>>>(
            rowptrR, NP1_R, colsrtR, valsrtR, Yprot, 1024,
            Yrna, 1024, 256, nullptr, nullptr, out, 256, E);
        spmm_csr_kernel<64, 2><<<NPROT, blk, 0, stream>>>(
            rowptrP, NP1_P, colsrtP, valsrtP, Yrna, 1024,
            Yprot, 1024, 256, nullptr, nullptr, out + (size_t)NRNA * 256, 256, E);
    } else {
        // fallback: CSR lives in d_out -> unfused accumulate, then relu_out
        spmm_csr_kernel<64, 0><<<NRNA, blk, 0, stream>>>(
            rowptrR, NP1_R, colsrtR, valsrtR, Yprot, 1024,
            Yrna, 1024, 256, nullptr, nullptr, nullptr, 0, E);
        spmm_csr_kernel<64, 0><<<NPROT, blk, 0, stream>>>(
            rowptrP, NP1_P, colsrtP, valsrtP, Yrna, 1024,
            Yprot, 1024, 256, nullptr, nullptr, nullptr, 0, E);
        relu_out_kernel<256><<<(NRNA * 256) / 256, blk, 0, stream>>>(Yrna, 1024, 256, out, NRNA);
        relu_out_kernel<256><<<(NPROT * 256) / 256, blk, 0, stream>>>(Yprot, 1024, 256,
                                                                      out + (size_t)NRNA * 256, NPROT);
    }
}

// Round 5
// 1533.449 us; speedup vs baseline: 3.2762x; 1.0656x over previous
//
#include <hip/hip_runtime.h>
#include <hip/hip_bf16.h>

// ---------------------------------------------------------------------------
// StackGCNEncoder on MI355X — round 5:
//   + tmp stored as bf16 (gather traffic halved; base stays f32)
//   + GEMM writes dual-format epilogue (bf16 tmp blocks / f32 base blocks)
//   + RNA+PROT merged into one GEMM dispatch per layer (M = 70144)
//   + buffers aliased across layers (Tmp1 aliases Tmp0, YbaseL1 aliases YbaseL0)
// ---------------------------------------------------------------------------

typedef unsigned short u16;
typedef short s16x8 __attribute__((ext_vector_type(8)));
typedef float f32x4 __attribute__((ext_vector_type(4)));
typedef __attribute__((ext_vector_type(4))) unsigned short u16x4;
typedef __attribute__((ext_vector_type(2))) unsigned short u16x2;

__device__ __forceinline__ u16 f2bf(float x) {            // RNE f32->bf16
    unsigned u = __float_as_uint(x);
    return (u16)((u + 0x7fff + ((u >> 16) & 1)) >> 16);
}
__device__ __forceinline__ float bf2f(u16 h) {
    return __uint_as_float(((unsigned)h) << 16);
}

__device__ __forceinline__ void gload16(const u16* g, u16* l) {
    __builtin_amdgcn_global_load_lds(
        (const __attribute__((address_space(1))) unsigned int*)g,
        (__attribute__((address_space(3))) unsigned int*)l,
        16, 0, 0);
}

// ---------------------------------------------------------------------------
// Split-bf16 GEMM: [T16|Yb] = A[Mpad][K] x B^T[N][K]. 128x128 tile, BK=32.
// Blocks with bn0 <  tmpw  write bf16 into T16 (ld ldt);
// blocks with bn0 >= tmpw  write f32 into Yb (ld ldb, col - tmpw).
// 1-D grid, bijective XCD swizzle; bx = N-block (fastest), N-blocks = 1<<nxshift.
// Grid covers ALL Mpad rows (pad rows have zeroed A -> zero output).
// ---------------------------------------------------------------------------
__global__ __launch_bounds__(256)
void gemm_split_kernel(const u16* __restrict__ Ah, const u16* __restrict__ Al,
                       const u16* __restrict__ Bh, const u16* __restrict__ Bl,
                       u16* __restrict__ T16, int ldt,
                       float* __restrict__ Yb, int ldb, int tmpw,
                       int K, int nxmask, int nxshift)
{
    __shared__ u16 lds[2][4][128 * 32];   // 64 KB

    // bijective XCD swizzle: consecutive lin ids -> same XCD
    const int nwg = gridDim.x;
    const int q   = nwg >> 3, r8 = nwg & 7;
    const int xcd = blockIdx.x & 7, pos = blockIdx.x >> 3;
    const int lin = (xcd < r8 ? xcd * (q + 1) : r8 * (q + 1) + (xcd - r8) * q) + pos;
    const int bm0 = (lin >> nxshift) * 128;
    const int bn0 = (lin & nxmask) * 128;

    const int tid  = threadIdx.x;
    const int lane = tid & 63;
    const int wid  = tid >> 6;
    const int wr   = wid >> 1;
    const int wc   = wid & 1;

    const int srow = tid >> 2;
    const int scol = (tid & 3) * 8;
    const size_t aoff0 = (size_t)(bm0 + srow) * K + scol;
    const size_t aoff1 = (size_t)(bm0 + srow + 64) * K + scol;
    const size_t boff0 = (size_t)(bn0 + srow) * K + scol;
    const size_t boff1 = (size_t)(bn0 + srow + 64) * K + scol;
    const int c0 = tid * 8;
    const int c1 = 2048 + tid * 8;

    u16* L0 = &lds[0][0][0];

    f32x4 zero = {0.f, 0.f, 0.f, 0.f};
    f32x4 acc[4][4];
    #pragma unroll
    for (int i = 0; i < 4; ++i)
        #pragma unroll
        for (int j = 0; j < 4; ++j) acc[i][j] = zero;

    const int a_fr = (wr * 64 + (lane & 15)) * 32 + (lane >> 4) * 8;
    const int b_fr = (wc * 64 + (lane & 15)) * 32 + (lane >> 4) * 8;

    const int nk = K >> 5;

    {
        u16* L = L0;
        gload16(Ah + aoff0, L + c0);            gload16(Ah + aoff1, L + c1);
        gload16(Al + aoff0, L + 4096 + c0);     gload16(Al + aoff1, L + 4096 + c1);
        gload16(Bh + boff0, L + 8192 + c0);     gload16(Bh + boff1, L + 8192 + c1);
        gload16(Bl + boff0, L + 12288 + c0);    gload16(Bl + boff1, L + 12288 + c1);
    }

    int cur = 0;
    for (int t = 0; t < nk; ++t) {
        __syncthreads();
        if (t + 1 < nk) {
            const int k0 = (t + 1) * 32;
            u16* L = L0 + (cur ^ 1) * 16384;
            gload16(Ah + aoff0 + k0, L + c0);         gload16(Ah + aoff1 + k0, L + c1);
            gload16(Al + aoff0 + k0, L + 4096 + c0);  gload16(Al + aoff1 + k0, L + 4096 + c1);
            gload16(Bh + boff0 + k0, L + 8192 + c0);  gload16(Bh + boff1 + k0, L + 8192 + c1);
            gload16(Bl + boff0 + k0, L + 12288 + c0); gload16(Bl + boff1 + k0, L + 12288 + c1);
        }
        const u16* L = L0 + cur * 16384;
        s16x8 bh[4], bl[4];
        #pragma unroll
        for (int nf = 0; nf < 4; ++nf) {
            const int o = b_fr + nf * 512;
            bh[nf] = *(const s16x8*)(L + 8192 + o);
            bl[nf] = *(const s16x8*)(L + 12288 + o);
        }
        #pragma unroll
        for (int mf = 0; mf < 4; ++mf) {
            const int o = a_fr + mf * 512;
            s16x8 ahv = *(const s16x8*)(L + o);
            s16x8 alv = *(const s16x8*)(L + 4096 + o);
            #pragma unroll
            for (int nf = 0; nf < 4; ++nf) {
                acc[mf][nf] = __builtin_amdgcn_mfma_f32_16x16x32_bf16(ahv, bh[nf], acc[mf][nf], 0, 0, 0);
                acc[mf][nf] = __builtin_amdgcn_mfma_f32_16x16x32_bf16(ahv, bl[nf], acc[mf][nf], 0, 0, 0);
                acc[mf][nf] = __builtin_amdgcn_mfma_f32_16x16x32_bf16(alv, bh[nf], acc[mf][nf], 0, 0, 0);
            }
        }
        cur ^= 1;
    }

    // epilogue: whole block is either tmp (bf16) or base (f32) since tmpw%128==0
    if (bn0 < tmpw) {
        #pragma unroll
        for (int mf = 0; mf < 4; ++mf) {
            const int row0 = bm0 + wr * 64 + mf * 16 + (lane >> 4) * 4;
            #pragma unroll
            for (int nf = 0; nf < 4; ++nf) {
                const int col = bn0 + wc * 64 + nf * 16 + (lane & 15);
                #pragma unroll
                for (int r = 0; r < 4; ++r)
                    T16[(size_t)(row0 + r) * ldt + col] = f2bf(acc[mf][nf][r]);
            }
        }
    } else {
        #pragma unroll
        for (int mf = 0; mf < 4; ++mf) {
            const int row0 = bm0 + wr * 64 + mf * 16 + (lane >> 4) * 4;
            #pragma unroll
            for (int nf = 0; nf < 4; ++nf) {
                const int col = bn0 + wc * 64 + nf * 16 + (lane & 15) - tmpw;
                #pragma unroll
                for (int r = 0; r < 4; ++r)
                    Yb[(size_t)(row0 + r) * ldb + col] = acc[mf][nf][r];
            }
        }
    }
}

// ---------------------------------------------------------------------------
// f32 [M][K] -> hi/lo bf16 [Mpad][K], zero-padded rows. 4 elems/thread.
// ---------------------------------------------------------------------------
__global__ __launch_bounds__(256)
void split_kernel(const float* __restrict__ A, u16* __restrict__ Hh,
                  u16* __restrict__ Hl, int M, int kshift)
{
    const size_t g  = (size_t)blockIdx.x * 256 + threadIdx.x;
    const size_t i4 = g * 4;
    const int row   = (int)(i4 >> kshift);
    f32x4 v = {0.f, 0.f, 0.f, 0.f};
    if (row < M) v = *(const f32x4*)(A + i4);
    u16x4 h, l;
    #pragma unroll
    for (int j = 0; j < 4; ++j) {
        u16 hb = f2bf(v[j]);
        h[j] = hb;
        l[j] = f2bf(v[j] - bf2f(hb));
    }
    *(u16x4*)(Hh + i4) = h;
    *(u16x4*)(Hl + i4) = l;
}

__global__ __launch_bounds__(256)
void zero2_u16_kernel(u16* __restrict__ a, u16* __restrict__ b, int n)
{
    int i = blockIdx.x * 256 + threadIdx.x;
    if (i < n) { a[i] = 0; b[i] = 0; }
}

// ---------------------------------------------------------------------------
// CSR build: zero -> histogram -> block scan -> aux scan -> finalize -> fill
// ---------------------------------------------------------------------------
__global__ __launch_bounds__(256)
void zero_i32_kernel(int* __restrict__ p, int n)
{
    int i = blockIdx.x * 256 + threadIdx.x;
    if (i < n) p[i] = 0;
}

__global__ __launch_bounds__(256)
void hist_kernel(const int* __restrict__ rows, int* __restrict__ counts,
                 int N, int E)
{
    int s = blockIdx.y;
    int e = blockIdx.x * 256 + threadIdx.x;
    if (e < E) atomicAdd(counts + s * N + rows[(size_t)s * E + e], 1);
}

__global__ __launch_bounds__(256)
void scan_block_kernel(const int* __restrict__ counts, int* __restrict__ rowptr,
                       int* __restrict__ blocksum, int N, int np1, int NB)
{
    __shared__ int sd[256];
    int s = blockIdx.y;
    int i = blockIdx.x * 256 + threadIdx.x;
    int tid = threadIdx.x;
    int v = (i < N) ? counts[s * N + i] : 0;
    sd[tid] = v;
    __syncthreads();
    #pragma unroll
    for (int off = 1; off < 256; off <<= 1) {
        int t = (tid >= off) ? sd[tid - off] : 0;
        __syncthreads();
        sd[tid] += t;
        __syncthreads();
    }
    if (i < N) rowptr[s * np1 + i] = sd[tid] - v;
    if (tid == 255) blocksum[s * NB + blockIdx.x] = sd[255];
}

__global__ __launch_bounds__(256)
void scan_aux_kernel(int* __restrict__ blocksum, int NB)
{
    __shared__ int sd[256];
    int s = blockIdx.x;
    int tid = threadIdx.x;
    int v = (tid < NB) ? blocksum[s * NB + tid] : 0;
    sd[tid] = v;
    __syncthreads();
    #pragma unroll
    for (int off = 1; off < 256; off <<= 1) {
        int t = (tid >= off) ? sd[tid - off] : 0;
        __syncthreads();
        sd[tid] += t;
        __syncthreads();
    }
    if (tid < NB) blocksum[s * NB + tid] = sd[tid] - v;
}

__global__ __launch_bounds__(256)
void finalize_rowptr_kernel(int* __restrict__ rowptr, const int* __restrict__ blocksum,
                            int* __restrict__ cursor, int N, int np1, int NB, int E)
{
    int s = blockIdx.y;
    int i = blockIdx.x * 256 + threadIdx.x;
    if (i < N) {
        int v = rowptr[s * np1 + i] + blocksum[s * NB + blockIdx.x];
        rowptr[s * np1 + i] = v;
        cursor[s * N + i] = v;
    }
    if (i == N) rowptr[s * np1 + N] = E;
}

__global__ __launch_bounds__(256)
void fill_csr_kernel(const int* __restrict__ rows, const int* __restrict__ cols,
                     const float* __restrict__ vals, int* __restrict__ cursor,
                     int* __restrict__ colsrt, float* __restrict__ valsrt,
                     int N, int E)
{
    int s = blockIdx.y;
    int e = blockIdx.x * 256 + threadIdx.x;
    if (e < E) {
        size_t idx = (size_t)s * E + e;
        int r = rows[idx];
        int pos = atomicAdd(cursor + s * N + r, 1);
        colsrt[(size_t)s * E + pos] = cols[idx];
        valsrt[(size_t)s * E + pos] = vals[idx];
    }
}

// ---------------------------------------------------------------------------
// CSR SpMM over bf16 tmp: grid (N_out), 4 waves = 4 relations, unroll-4.
// MODE 0: Base[r][col] += acc                      (fallback L1)
// MODE 1: OutH/OutL[r][col] = split(relu(Base+acc))  (L0 -> layer-1 A)
// MODE 2: OutF[r][col]      = relu(Base+acc)         (L1 -> d_out)
// ---------------------------------------------------------------------------
template<int KCH, int MODE>
__global__ __launch_bounds__(256)
void spmm_csr_kernel(const int* __restrict__ rowptr, int np1,
                     const int* __restrict__ colsrt, const float* __restrict__ valsrt,
                     const u16* __restrict__ In, int ldi,
                     float* __restrict__ Base, int ldb,
                     u16* __restrict__ OutH, u16* __restrict__ OutL,
                     float* __restrict__ OutF, int ldo, int E)
{
    const int r    = blockIdx.x;
    const int s    = threadIdx.x >> 6;
    const int lane = threadIdx.x & 63;
    int e0 = rowptr[s * np1 + r];
    int e1 = rowptr[s * np1 + r + 1];
    if (MODE == 0 && e0 == e1) return;   // wave-uniform
    const int* cs   = colsrt + (size_t)s * E;
    const float* vs = valsrt + (size_t)s * E;

    if (KCH == 128) {
        const int col = s * 128 + lane * 2;
        float ax = 0.f, ay = 0.f;
        int e = e0;
        for (; e + 3 < e1; e += 4) {
            int   ca = cs[e],   cb = cs[e+1], cc = cs[e+2], cd = cs[e+3];
            float va = vs[e],   vb = vs[e+1], vc = vs[e+2], vd = vs[e+3];
            u16x2 xa = *(const u16x2*)(In + (size_t)ca * ldi + col);
            u16x2 xb = *(const u16x2*)(In + (size_t)cb * ldi + col);
            u16x2 xc = *(const u16x2*)(In + (size_t)cc * ldi + col);
            u16x2 xd = *(const u16x2*)(In + (size_t)cd * ldi + col);
            ax += va * bf2f(xa[0]) + vb * bf2f(xb[0]) + vc * bf2f(xc[0]) + vd * bf2f(xd[0]);
            ay += va * bf2f(xa[1]) + vb * bf2f(xb[1]) + vc * bf2f(xc[1]) + vd * bf2f(xd[1]);
        }
        for (; e < e1; ++e) {
            int c = cs[e]; float v = vs[e];
            u16x2 x = *(const u16x2*)(In + (size_t)c * ldi + col);
            ax += v * bf2f(x[0]);  ay += v * bf2f(x[1]);
        }
        if (MODE == 0) {
            float2* o = (float2*)(Base + (size_t)r * ldb + col);
            float2 cv = *o; cv.x += ax; cv.y += ay; *o = cv;
        } else {
            const float2 b = *(const float2*)(Base + (size_t)r * ldb + col);
            float fx = fmaxf(b.x + ax, 0.f), fy = fmaxf(b.y + ay, 0.f);
            u16 hx = f2bf(fx), hy = f2bf(fy);
            u16x2 h = {hx, hy};
            u16x2 l = {f2bf(fx - bf2f(hx)), f2bf(fy - bf2f(hy))};
            *(u16x2*)(OutH + (size_t)r * ldo + col) = h;
            *(u16x2*)(OutL + (size_t)r * ldo + col) = l;
        }
    } else {   // KCH == 64
        const int col = s * 64 + lane;
        float acc = 0.f;
        int e = e0;
        for (; e + 3 < e1; e += 4) {
            int   ca = cs[e],   cb = cs[e+1], cc = cs[e+2], cd = cs[e+3];
            float va = vs[e],   vb = vs[e+1], vc = vs[e+2], vd = vs[e+3];
            acc += va * bf2f(In[(size_t)ca * ldi + col]) + vb * bf2f(In[(size_t)cb * ldi + col])
                 + vc * bf2f(In[(size_t)cc * ldi + col]) + vd * bf2f(In[(size_t)cd * ldi + col]);
        }
        for (; e < e1; ++e)
            acc += vs[e] * bf2f(In[(size_t)cs[e] * ldi + col]);
        if (MODE == 0) {
            Base[(size_t)r * ldb + col] += acc;
        } else {
            OutF[(size_t)r * ldo + col] = fmaxf(Base[(size_t)r * ldb + col] + acc, 0.f);
        }
    }
}

// fallback-only final relu (Base ld 256)
__global__ __launch_bounds__(256)
void relu_out_kernel(const float* __restrict__ Z, float* __restrict__ out, int M)
{
    int g = blockIdx.x * 256 + threadIdx.x;
    if (g >= M * 256) return;
    out[g] = fmaxf(Z[g], 0.f);
}

// ---------------------------------------------------------------------------
// weight packing (transposed [N][K], hi/lo)
// ---------------------------------------------------------------------------
__global__ __launch_bounds__(256)
void pack_b0_split_kernel(const float* __restrict__ w0, const float* __restrict__ sw0,
                          u16* __restrict__ Bh, u16* __restrict__ Bl)
{
    int g = blockIdx.x * 256 + threadIdx.x;
    int j = g >> 10, d = g & 1023;
    float v;
    if (j < 512) v = w0[((size_t)(j >> 7) * 1024 + d) * 128 + (j & 127)];
    else         v = sw0[(size_t)d * 512 + (j - 512)];
    u16 h = f2bf(v);
    Bh[g] = h;
    Bl[g] = f2bf(v - bf2f(h));
}

__global__ __launch_bounds__(256)
void pack_b1_split_kernel(const float* __restrict__ w1, const float* __restrict__ sw1,
                          u16* __restrict__ Bh, u16* __restrict__ Bl)
{
    int g = blockIdx.x * 256 + threadIdx.x;
    int j = g >> 9, d = g & 511;
    float v;
    if (j < 256) v = w1[((size_t)(j >> 6) * 512 + d) * 64 + (j & 63)];
    else         v = sw1[(size_t)d * 256 + (j - 256)];
    u16 h = f2bf(v);
    Bh[g] = h;
    Bl[g] = f2bf(v - bf2f(h));
}

extern "C" void kernel_launch(void* const* d_in, const int* in_sizes, int n_in,
                              void* d_out, int out_size, void* d_ws, size_t ws_size,
                              hipStream_t stream)
{
    const int*   rna_rows  = (const int*)  d_in[0];
    const int*   rna_cols  = (const int*)  d_in[1];
    const float* rna_vals  = (const float*)d_in[2];
    const int*   prot_rows = (const int*)  d_in[3];
    const int*   prot_cols = (const int*)  d_in[4];
    const float* prot_vals = (const float*)d_in[5];
    const float* H_rna     = (const float*)d_in[6];
    const float* H_prot    = (const float*)d_in[7];
    const float* w0        = (const float*)d_in[8];
    const float* sw0       = (const float*)d_in[9];
    const float* w1        = (const float*)d_in[10];
    const float* sw1       = (const float*)d_in[11];

    const int NRNA = 50000, NPROT = 20000, S = 4, E = 500000;
    const int MP_RNA = 50048, MP_PROT = 20096;
    const int MP_ALL = MP_RNA + MP_PROT;           // 70144 = 548 * 128
    const int NP1_R = NRNA + 1, NP1_P = NPROT + 1;
    const int NB_R = (NRNA + 255) / 256;
    const int NB_P = (NPROT + 255) / 256;
    const int EB   = (E + 255) / 256;

    // --- ws layout ---
    char* ws = (char*)d_ws;
    size_t off = 0;
    float* Ybase = (float*)(ws + off); off += (size_t)MP_ALL * 512 * 4;   // L0 ld512 / L1 ld256
    u16*   Tmp0  = (u16*)  (ws + off); off += (size_t)MP_ALL * 512 * 2;   // L0 ld512; L1 aliases ld256
    u16*   Ahbig = (u16*)  (ws + off); off += (size_t)MP_ALL * 1024 * 2;
    u16*   Albig = (u16*)  (ws + off); off += (size_t)MP_ALL * 1024 * 2;
    u16*   B0h   = (u16*)  (ws + off); off += (size_t)1024 * 1024 * 2;
    u16*   B0l   = (u16*)  (ws + off); off += (size_t)1024 * 1024 * 2;
    u16*   B1h   = (u16*)  (ws + off); off += (size_t)512 * 512 * 2;
    u16*   B1l   = (u16*)  (ws + off); off += (size_t)512 * 512 * 2;
    size_t base_bytes = off;

    u16* Tmp1 = Tmp0;                               // ld 256, aliases Tmp0 (L0 reads done)
    // layer-1 A views carved from Ahbig/Albig (contiguous [MP_ALL][512]):
    u16* AhR = Ahbig;
    u16* AlR = Albig;
    u16* AhP = Ahbig + (size_t)MP_RNA * 512;
    u16* AlP = Albig + (size_t)MP_RNA * 512;

    // CSR scratch size
    size_t csr_bytes = 0;
    csr_bytes += (size_t)S * E * 4 * 2 * 2;
    csr_bytes += ((size_t)S * (NRNA * 2 + NP1_R + NB_R)) * 4;
    csr_bytes += ((size_t)S * (NPROT * 2 + NP1_P + NB_P)) * 4;
    const bool csr_in_ws = (ws_size >= base_bytes + csr_bytes);

    char* csr = csr_in_ws ? (ws + base_bytes) : (char*)d_out;
    size_t coff = 0;
    int*   colsrtR = (int*)  (csr + coff); coff += (size_t)S * E * 4;
    float* valsrtR = (float*)(csr + coff); coff += (size_t)S * E * 4;
    int*   colsrtP = (int*)  (csr + coff); coff += (size_t)S * E * 4;
    float* valsrtP = (float*)(csr + coff); coff += (size_t)S * E * 4;
    int*   countsR = (int*)  (csr + coff); coff += (size_t)S * NRNA * 4;
    int*   rowptrR = (int*)  (csr + coff); coff += (size_t)S * NP1_R * 4;
    int*   cursorR = (int*)  (csr + coff); coff += (size_t)S * NRNA * 4;
    int*   bsumR   = (int*)  (csr + coff); coff += (size_t)S * NB_R * 4;
    int*   countsP = (int*)  (csr + coff); coff += (size_t)S * NPROT * 4;
    int*   rowptrP = (int*)  (csr + coff); coff += (size_t)S * NP1_P * 4;
    int*   cursorP = (int*)  (csr + coff); coff += (size_t)S * NPROT * 4;
    int*   bsumP   = (int*)  (csr + coff); coff += (size_t)S * NB_P * 4;

    dim3 blk(256);
    float* out = (float*)d_out;

    // --- pack weights ---
    pack_b0_split_kernel<<<(1024 * 1024) / 256, blk, 0, stream>>>(w0, sw0, B0h, B0l);
    pack_b1_split_kernel<<<(512 * 512) / 256, blk, 0, stream>>>(w1, sw1, B1h, B1l);

    // --- CSR build (once; reused by both layers) ---
    zero_i32_kernel<<<(S * NRNA + 255) / 256, blk, 0, stream>>>(countsR, S * NRNA);
    zero_i32_kernel<<<(S * NPROT + 255) / 256, blk, 0, stream>>>(countsP, S * NPROT);
    hist_kernel<<<dim3(EB, S), blk, 0, stream>>>(rna_rows, countsR, NRNA, E);
    hist_kernel<<<dim3(EB, S), blk, 0, stream>>>(prot_rows, countsP, NPROT, E);
    scan_block_kernel<<<dim3(NB_R, S), blk, 0, stream>>>(countsR, rowptrR, bsumR, NRNA, NP1_R, NB_R);
    scan_block_kernel<<<dim3(NB_P, S), blk, 0, stream>>>(countsP, rowptrP, bsumP, NPROT, NP1_P, NB_P);
    scan_aux_kernel<<<S, blk, 0, stream>>>(bsumR, NB_R);
    scan_aux_kernel<<<S, blk, 0, stream>>>(bsumP, NB_P);
    finalize_rowptr_kernel<<<dim3(NB_R, S), blk, 0, stream>>>(rowptrR, bsumR, cursorR, NRNA, NP1_R, NB_R, E);
    finalize_rowptr_kernel<<<dim3(NB_P, S), blk, 0, stream>>>(rowptrP, bsumP, cursorP, NPROT, NP1_P, NB_P, E);
    fill_csr_kernel<<<dim3(EB, S), blk, 0, stream>>>(rna_rows, rna_cols, rna_vals,
                                                     cursorR, colsrtR, valsrtR, NRNA, E);
    fill_csr_kernel<<<dim3(EB, S), blk, 0, stream>>>(prot_rows, prot_cols, prot_vals,
                                                     cursorP, colsrtP, valsrtP, NPROT, E);

    // --- layer 0: split (RNA + PROT concatenated over M) + one GEMM ---
    split_kernel<<<MP_RNA, blk, 0, stream>>>(H_rna, Ahbig, Albig, NRNA, 10);
    split_kernel<<<MP_PROT, blk, 0, stream>>>(H_prot, Ahbig + (size_t)MP_RNA * 1024,
                                              Albig + (size_t)MP_RNA * 1024, NPROT, 10);
    gemm_split_kernel<<<8 * (MP_ALL / 128), blk, 0, stream>>>(
        Ahbig, Albig, B0h, B0l, Tmp0, 512, Ybase, 512, 512, 1024, 7, 3);

    // --- layer 0 SpMM fused: relu+split -> layer-1 A operands (bf16) ---
    spmm_csr_kernel<128, 1><<<NRNA, blk, 0, stream>>>(
        rowptrR, NP1_R, colsrtR, valsrtR,
        Tmp0 + (size_t)MP_RNA * 512, 512,          // gather prot tmp
        Ybase, 512, AhR, AlR, nullptr, 512, E);
    spmm_csr_kernel<128, 1><<<NPROT, blk, 0, stream>>>(
        rowptrP, NP1_P, colsrtP, valsrtP,
        Tmp0, 512,                                  // gather rna tmp
        Ybase + (size_t)MP_RNA * 512, 512, AhP, AlP, nullptr, 512, E);

    // --- zero layer-1 A pad rows ---
    zero2_u16_kernel<<<(48 * 512 + 255) / 256, blk, 0, stream>>>(
        AhR + (size_t)NRNA * 512, AlR + (size_t)NRNA * 512, 48 * 512);
    zero2_u16_kernel<<<(96 * 512 + 255) / 256, blk, 0, stream>>>(
        AhP + (size_t)NPROT * 512, AlP + (size_t)NPROT * 512, 96 * 512);

    // --- layer 1: one merged GEMM (N=K=512) ---
    gemm_split_kernel<<<4 * (MP_ALL / 128), blk, 0, stream>>>(
        Ahbig, Albig, B1h, B1l, Tmp1, 256, Ybase, 256, 256, 512, 3, 2);

    // --- layer 1 SpMM ---
    if (csr_in_ws) {
        spmm_csr_kernel<64, 2><<<NRNA, blk, 0, stream>>>(
            rowptrR, NP1_R, colsrtR, valsrtR,
            Tmp1 + (size_t)MP_RNA * 256, 256,
            Ybase, 256, nullptr, nullptr, out, 256, E);
        spmm_csr_kernel<64, 2><<<NPROT, blk, 0, stream>>>(
            rowptrP, NP1_P, colsrtP, valsrtP,
            Tmp1, 256,
            Ybase + (size_t)MP_RNA * 256, 256, nullptr, nullptr,
            out + (size_t)NRNA * 256, 256, E);
    } else {
        // CSR lives in d_out -> accumulate into Ybase, then relu to d_out
        spmm_csr_kernel<64, 0><<<NRNA, blk, 0, stream>>>(
            rowptrR, NP1_R, colsrtR, valsrtR,
            Tmp1 + (size_t)MP_RNA * 256, 256,
            Ybase, 256, nullptr, nullptr, nullptr, 0, E);
        spmm_csr_kernel<64, 0><<<NPROT, blk, 0, stream>>>(
            rowptrP, NP1_P, colsrtP, valsrtP,
            Tmp1, 256,
            Ybase + (size_t)MP_RNA * 256, 256, nullptr, nullptr, nullptr, 0, E);
        relu_out_kernel<<<(NRNA * 256) / 256, blk, 0, stream>>>(Ybase, out, NRNA);
        relu_out_kernel<<<(NPROT * 256) / 256, blk, 0, stream>>>(
            Ybase + (size_t)MP_RNA * 256, out + (size_t)NRNA * 256, NPROT);
    }
}

// Round 6
// 1523.715 us; speedup vs baseline: 3.2971x; 1.0064x over previous
//
#include <hip/hip_runtime.h>
#include <hip/hip_bf16.h>

// ---------------------------------------------------------------------------
// StackGCNEncoder on MI355X — round 6:
//   + T2 XOR chunk-swizzle in GEMM LDS (pre-swizzled global source for
//     global_load_lds + same XOR on ds_read) -> kills 8-way bank conflicts
//   + CSR edges packed as int2{col, val_bits} (half the scattered stores /
//     edge loads)
// Everything else as round 5 (bf16 tmp, merged GEMMs, fused spmm epilogues).
// ---------------------------------------------------------------------------

typedef unsigned short u16;
typedef short s16x8 __attribute__((ext_vector_type(8)));
typedef float f32x4 __attribute__((ext_vector_type(4)));
typedef __attribute__((ext_vector_type(4))) unsigned short u16x4;
typedef __attribute__((ext_vector_type(2))) unsigned short u16x2;

__device__ __forceinline__ u16 f2bf(float x) {            // RNE f32->bf16
    unsigned u = __float_as_uint(x);
    return (u16)((u + 0x7fff + ((u >> 16) & 1)) >> 16);
}
__device__ __forceinline__ float bf2f(u16 h) {
    return __uint_as_float(((unsigned)h) << 16);
}

__device__ __forceinline__ void gload16(const u16* g, u16* l) {
    __builtin_amdgcn_global_load_lds(
        (const __attribute__((address_space(1))) unsigned int*)g,
        (__attribute__((address_space(3))) unsigned int*)l,
        16, 0, 0);
}

// ---------------------------------------------------------------------------
// Split-bf16 GEMM: [T16|Yb] = A[Mpad][K] x B^T[N][K]. 128x128 tile, BK=32.
// LDS layout: [128 rows][4 chunks of 8 u16], physical chunk = logical ^ ((row>>1)&3).
// Staging pre-swizzles the GLOBAL source chunk; LDS dest stays linear
// (global_load_lds requirement). All ds_reads apply the same XOR.
// ---------------------------------------------------------------------------
__global__ __launch_bounds__(256)
void gemm_split_kernel(const u16* __restrict__ Ah, const u16* __restrict__ Al,
                       const u16* __restrict__ Bh, const u16* __restrict__ Bl,
                       u16* __restrict__ T16, int ldt,
                       float* __restrict__ Yb, int ldb, int tmpw,
                       int K, int nxmask, int nxshift)
{
    __shared__ u16 lds[2][4][128 * 32];   // 64 KB

    // bijective XCD swizzle: consecutive lin ids -> same XCD
    const int nwg = gridDim.x;
    const int q   = nwg >> 3, r8 = nwg & 7;
    const int xcd = blockIdx.x & 7, pos = blockIdx.x >> 3;
    const int lin = (xcd < r8 ? xcd * (q + 1) : r8 * (q + 1) + (xcd - r8) * q) + pos;
    const int bm0 = (lin >> nxshift) * 128;
    const int bn0 = (lin & nxmask) * 128;

    const int tid  = threadIdx.x;
    const int lane = tid & 63;
    const int wid  = tid >> 6;
    const int wr   = wid >> 1;
    const int wc   = wid & 1;

    // staging: thread t -> physical (row = t>>2 [+64], chunk p = t&3).
    // source logical chunk = p ^ ((row>>1)&3); rows r and r+64 share mask bits.
    const int srow = tid >> 2;
    const int scol = ((tid & 3) ^ ((tid >> 3) & 3)) * 8;   // u16 units
    const size_t aoff0 = (size_t)(bm0 + srow) * K + scol;
    const size_t aoff1 = (size_t)(bm0 + srow + 64) * K + scol;
    const size_t boff0 = (size_t)(bn0 + srow) * K + scol;
    const size_t boff1 = (size_t)(bn0 + srow + 64) * K + scol;
    const int c0 = tid * 8;               // linear LDS dest (u16 units)
    const int c1 = 2048 + tid * 8;

    u16* L0 = &lds[0][0][0];

    f32x4 zero = {0.f, 0.f, 0.f, 0.f};
    f32x4 acc[4][4];
    #pragma unroll
    for (int i = 0; i < 4; ++i)
        #pragma unroll
        for (int j = 0; j < 4; ++j) acc[i][j] = zero;

    // fragment reads: row = (lane&15) + 16*mf + 64*w, logical chunk = lane>>4.
    // mask = ((row>>1)&3) = ((lane>>1)&3)  (mf/w only touch row bits >=4)
    const int fchunk = (((lane >> 4) ^ ((lane >> 1) & 3))) * 8;
    const int a_fr = (wr * 64 + (lane & 15)) * 32 + fchunk;
    const int b_fr = (wc * 64 + (lane & 15)) * 32 + fchunk;

    const int nk = K >> 5;

    {
        u16* L = L0;
        gload16(Ah + aoff0, L + c0);            gload16(Ah + aoff1, L + c1);
        gload16(Al + aoff0, L + 4096 + c0);     gload16(Al + aoff1, L + 4096 + c1);
        gload16(Bh + boff0, L + 8192 + c0);     gload16(Bh + boff1, L + 8192 + c1);
        gload16(Bl + boff0, L + 12288 + c0);    gload16(Bl + boff1, L + 12288 + c1);
    }

    int cur = 0;
    for (int t = 0; t < nk; ++t) {
        __syncthreads();
        if (t + 1 < nk) {
            const int k0 = (t + 1) * 32;
            u16* L = L0 + (cur ^ 1) * 16384;
            gload16(Ah + aoff0 + k0, L + c0);         gload16(Ah + aoff1 + k0, L + c1);
            gload16(Al + aoff0 + k0, L + 4096 + c0);  gload16(Al + aoff1 + k0, L + 4096 + c1);
            gload16(Bh + boff0 + k0, L + 8192 + c0);  gload16(Bh + boff1 + k0, L + 8192 + c1);
            gload16(Bl + boff0 + k0, L + 12288 + c0); gload16(Bl + boff1 + k0, L + 12288 + c1);
        }
        const u16* L = L0 + cur * 16384;
        s16x8 bh[4], bl[4];
        #pragma unroll
        for (int nf = 0; nf < 4; ++nf) {
            const int o = b_fr + nf * 512;
            bh[nf] = *(const s16x8*)(L + 8192 + o);
            bl[nf] = *(const s16x8*)(L + 12288 + o);
        }
        #pragma unroll
        for (int mf = 0; mf < 4; ++mf) {
            const int o = a_fr + mf * 512;
            s16x8 ahv = *(const s16x8*)(L + o);
            s16x8 alv = *(const s16x8*)(L + 4096 + o);
            #pragma unroll
            for (int nf = 0; nf < 4; ++nf) {
                acc[mf][nf] = __builtin_amdgcn_mfma_f32_16x16x32_bf16(ahv, bh[nf], acc[mf][nf], 0, 0, 0);
                acc[mf][nf] = __builtin_amdgcn_mfma_f32_16x16x32_bf16(ahv, bl[nf], acc[mf][nf], 0, 0, 0);
                acc[mf][nf] = __builtin_amdgcn_mfma_f32_16x16x32_bf16(alv, bh[nf], acc[mf][nf], 0, 0, 0);
            }
        }
        cur ^= 1;
    }

    // epilogue: whole block is either tmp (bf16) or base (f32) since tmpw%128==0
    if (bn0 < tmpw) {
        #pragma unroll
        for (int mf = 0; mf < 4; ++mf) {
            const int row0 = bm0 + wr * 64 + mf * 16 + (lane >> 4) * 4;
            #pragma unroll
            for (int nf = 0; nf < 4; ++nf) {
                const int col = bn0 + wc * 64 + nf * 16 + (lane & 15);
                #pragma unroll
                for (int r = 0; r < 4; ++r)
                    T16[(size_t)(row0 + r) * ldt + col] = f2bf(acc[mf][nf][r]);
            }
        }
    } else {
        #pragma unroll
        for (int mf = 0; mf < 4; ++mf) {
            const int row0 = bm0 + wr * 64 + mf * 16 + (lane >> 4) * 4;
            #pragma unroll
            for (int nf = 0; nf < 4; ++nf) {
                const int col = bn0 + wc * 64 + nf * 16 + (lane & 15) - tmpw;
                #pragma unroll
                for (int r = 0; r < 4; ++r)
                    Yb[(size_t)(row0 + r) * ldb + col] = acc[mf][nf][r];
            }
        }
    }
}

// ---------------------------------------------------------------------------
// f32 [M][K] -> hi/lo bf16 [Mpad][K], zero-padded rows. 4 elems/thread.
// ---------------------------------------------------------------------------
__global__ __launch_bounds__(256)
void split_kernel(const float* __restrict__ A, u16* __restrict__ Hh,
                  u16* __restrict__ Hl, int M, int kshift)
{
    const size_t g  = (size_t)blockIdx.x * 256 + threadIdx.x;
    const size_t i4 = g * 4;
    const int row   = (int)(i4 >> kshift);
    f32x4 v = {0.f, 0.f, 0.f, 0.f};
    if (row < M) v = *(const f32x4*)(A + i4);
    u16x4 h, l;
    #pragma unroll
    for (int j = 0; j < 4; ++j) {
        u16 hb = f2bf(v[j]);
        h[j] = hb;
        l[j] = f2bf(v[j] - bf2f(hb));
    }
    *(u16x4*)(Hh + i4) = h;
    *(u16x4*)(Hl + i4) = l;
}

__global__ __launch_bounds__(256)
void zero2_u16_kernel(u16* __restrict__ a, u16* __restrict__ b, int n)
{
    int i = blockIdx.x * 256 + threadIdx.x;
    if (i < n) { a[i] = 0; b[i] = 0; }
}

// ---------------------------------------------------------------------------
// CSR build: zero -> histogram -> block scan -> aux scan -> finalize -> fill
// Edges stored packed: int2{col, float_bits(val)}.
// ---------------------------------------------------------------------------
__global__ __launch_bounds__(256)
void zero_i32_kernel(int* __restrict__ p, int n)
{
    int i = blockIdx.x * 256 + threadIdx.x;
    if (i < n) p[i] = 0;
}

__global__ __launch_bounds__(256)
void hist_kernel(const int* __restrict__ rows, int* __restrict__ counts,
                 int N, int E)
{
    int s = blockIdx.y;
    int e = blockIdx.x * 256 + threadIdx.x;
    if (e < E) atomicAdd(counts + s * N + rows[(size_t)s * E + e], 1);
}

__global__ __launch_bounds__(256)
void scan_block_kernel(const int* __restrict__ counts, int* __restrict__ rowptr,
                       int* __restrict__ blocksum, int N, int np1, int NB)
{
    __shared__ int sd[256];
    int s = blockIdx.y;
    int i = blockIdx.x * 256 + threadIdx.x;
    int tid = threadIdx.x;
    int v = (i < N) ? counts[s * N + i] : 0;
    sd[tid] = v;
    __syncthreads();
    #pragma unroll
    for (int off = 1; off < 256; off <<= 1) {
        int t = (tid >= off) ? sd[tid - off] : 0;
        __syncthreads();
        sd[tid] += t;
        __syncthreads();
    }
    if (i < N) rowptr[s * np1 + i] = sd[tid] - v;
    if (tid == 255) blocksum[s * NB + blockIdx.x] = sd[255];
}

__global__ __launch_bounds__(256)
void scan_aux_kernel(int* __restrict__ blocksum, int NB)
{
    __shared__ int sd[256];
    int s = blockIdx.x;
    int tid = threadIdx.x;
    int v = (tid < NB) ? blocksum[s * NB + tid] : 0;
    sd[tid] = v;
    __syncthreads();
    #pragma unroll
    for (int off = 1; off < 256; off <<= 1) {
        int t = (tid >= off) ? sd[tid - off] : 0;
        __syncthreads();
        sd[tid] += t;
        __syncthreads();
    }
    if (tid < NB) blocksum[s * NB + tid] = sd[tid] - v;
}

__global__ __launch_bounds__(256)
void finalize_rowptr_kernel(int* __restrict__ rowptr, const int* __restrict__ blocksum,
                            int* __restrict__ cursor, int N, int np1, int NB, int E)
{
    int s = blockIdx.y;
    int i = blockIdx.x * 256 + threadIdx.x;
    if (i < N) {
        int v = rowptr[s * np1 + i] + blocksum[s * NB + blockIdx.x];
        rowptr[s * np1 + i] = v;
        cursor[s * N + i] = v;
    }
    if (i == N) rowptr[s * np1 + N] = E;
}

__global__ __launch_bounds__(256)
void fill_csr_kernel(const int* __restrict__ rows, const int* __restrict__ cols,
                     const float* __restrict__ vals, int* __restrict__ cursor,
                     int2* __restrict__ ev, int N, int E)
{
    int s = blockIdx.y;
    int e = blockIdx.x * 256 + threadIdx.x;
    if (e < E) {
        size_t idx = (size_t)s * E + e;
        int r = rows[idx];
        int pos = atomicAdd(cursor + s * N + r, 1);
        ev[(size_t)s * E + pos] = make_int2(cols[idx], __float_as_int(vals[idx]));
    }
}

// ---------------------------------------------------------------------------
// CSR SpMM over bf16 tmp: grid (N_out), 4 waves = 4 relations, unroll-4.
// MODE 0: Base[r][col] += acc                        (fallback L1)
// MODE 1: OutH/OutL[r][col] = split(relu(Base+acc))  (L0 -> layer-1 A)
// MODE 2: OutF[r][col]      = relu(Base+acc)         (L1 -> d_out)
// ---------------------------------------------------------------------------
template<int KCH, int MODE>
__global__ __launch_bounds__(256)
void spmm_csr_kernel(const int* __restrict__ rowptr, int np1,
                     const int2* __restrict__ evg,
                     const u16* __restrict__ In, int ldi,
                     float* __restrict__ Base, int ldb,
                     u16* __restrict__ OutH, u16* __restrict__ OutL,
                     float* __restrict__ OutF, int ldo, int E)
{
    const int r    = blockIdx.x;
    const int s    = threadIdx.x >> 6;
    const int lane = threadIdx.x & 63;
    int e0 = rowptr[s * np1 + r];
    int e1 = rowptr[s * np1 + r + 1];
    if (MODE == 0 && e0 == e1) return;   // wave-uniform
    const int2* ev = evg + (size_t)s * E;

    if (KCH == 128) {
        const int col = s * 128 + lane * 2;
        float ax = 0.f, ay = 0.f;
        int e = e0;
        for (; e + 3 < e1; e += 4) {
            int2 pa = ev[e],   pb = ev[e+1], pc = ev[e+2], pd = ev[e+3];
            float va = __int_as_float(pa.y), vb = __int_as_float(pb.y);
            float vc = __int_as_float(pc.y), vd = __int_as_float(pd.y);
            u16x2 xa = *(const u16x2*)(In + (size_t)pa.x * ldi + col);
            u16x2 xb = *(const u16x2*)(In + (size_t)pb.x * ldi + col);
            u16x2 xc = *(const u16x2*)(In + (size_t)pc.x * ldi + col);
            u16x2 xd = *(const u16x2*)(In + (size_t)pd.x * ldi + col);
            ax += va * bf2f(xa[0]) + vb * bf2f(xb[0]) + vc * bf2f(xc[0]) + vd * bf2f(xd[0]);
            ay += va * bf2f(xa[1]) + vb * bf2f(xb[1]) + vc * bf2f(xc[1]) + vd * bf2f(xd[1]);
        }
        for (; e < e1; ++e) {
            int2 p = ev[e];
            float v = __int_as_float(p.y);
            u16x2 x = *(const u16x2*)(In + (size_t)p.x * ldi + col);
            ax += v * bf2f(x[0]);  ay += v * bf2f(x[1]);
        }
        if (MODE == 0) {
            float2* o = (float2*)(Base + (size_t)r * ldb + col);
            float2 cv = *o; cv.x += ax; cv.y += ay; *o = cv;
        } else {
            const float2 b = *(const float2*)(Base + (size_t)r * ldb + col);
            float fx = fmaxf(b.x + ax, 0.f), fy = fmaxf(b.y + ay, 0.f);
            u16 hx = f2bf(fx), hy = f2bf(fy);
            u16x2 h = {hx, hy};
            u16x2 l = {f2bf(fx - bf2f(hx)), f2bf(fy - bf2f(hy))};
            *(u16x2*)(OutH + (size_t)r * ldo + col) = h;
            *(u16x2*)(OutL + (size_t)r * ldo + col) = l;
        }
    } else {   // KCH == 64
        const int col = s * 64 + lane;
        float acc = 0.f;
        int e = e0;
        for (; e + 3 < e1; e += 4) {
            int2 pa = ev[e],   pb = ev[e+1], pc = ev[e+2], pd = ev[e+3];
            acc += __int_as_float(pa.y) * bf2f(In[(size_t)pa.x * ldi + col])
                 + __int_as_float(pb.y) * bf2f(In[(size_t)pb.x * ldi + col])
                 + __int_as_float(pc.y) * bf2f(In[(size_t)pc.x * ldi + col])
                 + __int_as_float(pd.y) * bf2f(In[(size_t)pd.x * ldi + col]);
        }
        for (; e < e1; ++e) {
            int2 p = ev[e];
            acc += __int_as_float(p.y) * bf2f(In[(size_t)p.x * ldi + col]);
        }
        if (MODE == 0) {
            Base[(size_t)r * ldb + col] += acc;
        } else {
            OutF[(size_t)r * ldo + col] = fmaxf(Base[(size_t)r * ldb + col] + acc, 0.f);
        }
    }
}

// fallback-only final relu (Base ld 256)
__global__ __launch_bounds__(256)
void relu_out_kernel(const float* __restrict__ Z, float* __restrict__ out, int M)
{
    int g = blockIdx.x * 256 + threadIdx.x;
    if (g >= M * 256) return;
    out[g] = fmaxf(Z[g], 0.f);
}

// ---------------------------------------------------------------------------
// weight packing (transposed [N][K], hi/lo)
// ---------------------------------------------------------------------------
__global__ __launch_bounds__(256)
void pack_b0_split_kernel(const float* __restrict__ w0, const float* __restrict__ sw0,
                          u16* __restrict__ Bh, u16* __restrict__ Bl)
{
    int g = blockIdx.x * 256 + threadIdx.x;
    int j = g >> 10, d = g & 1023;
    float v;
    if (j < 512) v = w0[((size_t)(j >> 7) * 1024 + d) * 128 + (j & 127)];
    else         v = sw0[(size_t)d * 512 + (j - 512)];
    u16 h = f2bf(v);
    Bh[g] = h;
    Bl[g] = f2bf(v - bf2f(h));
}

__global__ __launch_bounds__(256)
void pack_b1_split_kernel(const float* __restrict__ w1, const float* __restrict__ sw1,
                          u16* __restrict__ Bh, u16* __restrict__ Bl)
{
    int g = blockIdx.x * 256 + threadIdx.x;
    int j = g >> 9, d = g & 511;
    float v;
    if (j < 256) v = w1[((size_t)(j >> 6) * 512 + d) * 64 + (j & 63)];
    else         v = sw1[(size_t)d * 256 + (j - 256)];
    u16 h = f2bf(v);
    Bh[g] = h;
    Bl[g] = f2bf(v - bf2f(h));
}

extern "C" void kernel_launch(void* const* d_in, const int* in_sizes, int n_in,
                              void* d_out, int out_size, void* d_ws, size_t ws_size,
                              hipStream_t stream)
{
    const int*   rna_rows  = (const int*)  d_in[0];
    const int*   rna_cols  = (const int*)  d_in[1];
    const float* rna_vals  = (const float*)d_in[2];
    const int*   prot_rows = (const int*)  d_in[3];
    const int*   prot_cols = (const int*)  d_in[4];
    const float* prot_vals = (const float*)d_in[5];
    const float* H_rna     = (const float*)d_in[6];
    const float* H_prot    = (const float*)d_in[7];
    const float* w0        = (const float*)d_in[8];
    const float* sw0       = (const float*)d_in[9];
    const float* w1        = (const float*)d_in[10];
    const float* sw1       = (const float*)d_in[11];

    const int NRNA = 50000, NPROT = 20000, S = 4, E = 500000;
    const int MP_RNA = 50048, MP_PROT = 20096;
    const int MP_ALL = MP_RNA + MP_PROT;           // 70144 = 548 * 128
    const int NP1_R = NRNA + 1, NP1_P = NPROT + 1;
    const int NB_R = (NRNA + 255) / 256;
    const int NB_P = (NPROT + 255) / 256;
    const int EB   = (E + 255) / 256;

    // --- ws layout ---
    char* ws = (char*)d_ws;
    size_t off = 0;
    float* Ybase = (float*)(ws + off); off += (size_t)MP_ALL * 512 * 4;   // L0 ld512 / L1 ld256
    u16*   Tmp0  = (u16*)  (ws + off); off += (size_t)MP_ALL * 512 * 2;   // L0 ld512; L1 aliases ld256
    u16*   Ahbig = (u16*)  (ws + off); off += (size_t)MP_ALL * 1024 * 2;
    u16*   Albig = (u16*)  (ws + off); off += (size_t)MP_ALL * 1024 * 2;
    u16*   B0h   = (u16*)  (ws + off); off += (size_t)1024 * 1024 * 2;
    u16*   B0l   = (u16*)  (ws + off); off += (size_t)1024 * 1024 * 2;
    u16*   B1h   = (u16*)  (ws + off); off += (size_t)512 * 512 * 2;
    u16*   B1l   = (u16*)  (ws + off); off += (size_t)512 * 512 * 2;
    size_t base_bytes = off;

    u16* Tmp1 = Tmp0;                               // ld 256, aliases Tmp0
    u16* AhR = Ahbig;
    u16* AlR = Albig;
    u16* AhP = Ahbig + (size_t)MP_RNA * 512;
    u16* AlP = Albig + (size_t)MP_RNA * 512;

    // CSR scratch size (ev packed int2)
    size_t csr_bytes = 0;
    csr_bytes += (size_t)S * E * 8 * 2;                       // evR + evP
    csr_bytes += ((size_t)S * (NRNA * 2 + NP1_R + NB_R)) * 4;
    csr_bytes += ((size_t)S * (NPROT * 2 + NP1_P + NB_P)) * 4;
    const bool csr_in_ws = (ws_size >= base_bytes + csr_bytes);

    char* csr = csr_in_ws ? (ws + base_bytes) : (char*)d_out;
    size_t coff = 0;
    int2*  evR     = (int2*) (csr + coff); coff += (size_t)S * E * 8;
    int2*  evP     = (int2*) (csr + coff); coff += (size_t)S * E * 8;
    int*   countsR = (int*)  (csr + coff); coff += (size_t)S * NRNA * 4;
    int*   rowptrR = (int*)  (csr + coff); coff += (size_t)S * NP1_R * 4;
    int*   cursorR = (int*)  (csr + coff); coff += (size_t)S * NRNA * 4;
    int*   bsumR   = (int*)  (csr + coff); coff += (size_t)S * NB_R * 4;
    int*   countsP = (int*)  (csr + coff); coff += (size_t)S * NPROT * 4;
    int*   rowptrP = (int*)  (csr + coff); coff += (size_t)S * NP1_P * 4;
    int*   cursorP = (int*)  (csr + coff); coff += (size_t)S * NPROT * 4;
    int*   bsumP   = (int*)  (csr + coff); coff += (size_t)S * NB_P * 4;

    dim3 blk(256);
    float* out = (float*)d_out;

    // --- pack weights ---
    pack_b0_split_kernel<<<(1024 * 1024) / 256, blk, 0, stream>>>(w0, sw0, B0h, B0l);
    pack_b1_split_kernel<<<(512 * 512) / 256, blk, 0, stream>>>(w1, sw1, B1h, B1l);

    // --- CSR build (once; reused by both layers) ---
    zero_i32_kernel<<<(S * NRNA + 255) / 256, blk, 0, stream>>>(countsR, S * NRNA);
    zero_i32_kernel<<<(S * NPROT + 255) / 256, blk, 0, stream>>>(countsP, S * NPROT);
    hist_kernel<<<dim3(EB, S), blk, 0, stream>>>(rna_rows, countsR, NRNA, E);
    hist_kernel<<<dim3(EB, S), blk, 0, stream>>>(prot_rows, countsP, NPROT, E);
    scan_block_kernel<<<dim3(NB_R, S), blk, 0, stream>>>(countsR, rowptrR, bsumR, NRNA, NP1_R, NB_R);
    scan_block_kernel<<<dim3(NB_P, S), blk, 0, stream>>>(countsP, rowptrP, bsumP, NPROT, NP1_P, NB_P);
    scan_aux_kernel<<<S, blk, 0, stream>>>(bsumR, NB_R);
    scan_aux_kernel<<<S, blk, 0, stream>>>(bsumP, NB_P);
    finalize_rowptr_kernel<<<dim3(NB_R, S), blk, 0, stream>>>(rowptrR, bsumR, cursorR, NRNA, NP1_R, NB_R, E);
    finalize_rowptr_kernel<<<dim3(NB_P, S), blk, 0, stream>>>(rowptrP, bsumP, cursorP, NPROT, NP1_P, NB_P, E);
    fill_csr_kernel<<<dim3(EB, S), blk, 0, stream>>>(rna_rows, rna_cols, rna_vals,
                                                     cursorR, evR, NRNA, E);
    fill_csr_kernel<<<dim3(EB, S), blk, 0, stream>>>(prot_rows, prot_cols, prot_vals,
                                                     cursorP, evP, NPROT, E);

    // --- layer 0: split (RNA + PROT concatenated over M) + one GEMM ---
    split_kernel<<<MP_RNA, blk, 0, stream>>>(H_rna, Ahbig, Albig, NRNA, 10);
    split_kernel<<<MP_PROT, blk, 0, stream>>>(H_prot, Ahbig + (size_t)MP_RNA * 1024,
                                              Albig + (size_t)MP_RNA * 1024, NPROT, 10);
    gemm_split_kernel<<<8 * (MP_ALL / 128), blk, 0, stream>>>(
        Ahbig, Albig, B0h, B0l, Tmp0, 512, Ybase, 512, 512, 1024, 7, 3);

    // --- layer 0 SpMM fused: relu+split -> layer-1 A operands (bf16) ---
    spmm_csr_kernel<128, 1><<<NRNA, blk, 0, stream>>>(
        rowptrR, NP1_R, evR,
        Tmp0 + (size_t)MP_RNA * 512, 512,
        Ybase, 512, AhR, AlR, nullptr, 512, E);
    spmm_csr_kernel<128, 1><<<NPROT, blk, 0, stream>>>(
        rowptrP, NP1_P, evP,
        Tmp0, 512,
        Ybase + (size_t)MP_RNA * 512, 512, AhP, AlP, nullptr, 512, E);

    // --- zero layer-1 A pad rows ---
    zero2_u16_kernel<<<(48 * 512 + 255) / 256, blk, 0, stream>>>(
        AhR + (size_t)NRNA * 512, AlR + (size_t)NRNA * 512, 48 * 512);
    zero2_u16_kernel<<<(96 * 512 + 255) / 256, blk, 0, stream>>>(
        AhP + (size_t)NPROT * 512, AlP + (size_t)NPROT * 512, 96 * 512);

    // --- layer 1: one merged GEMM (N=K=512) ---
    gemm_split_kernel<<<4 * (MP_ALL / 128), blk, 0, stream>>>(
        Ahbig, Albig, B1h, B1l, Tmp1, 256, Ybase, 256, 256, 512, 3, 2);

    // --- layer 1 SpMM ---
    if (csr_in_ws) {
        spmm_csr_kernel<64, 2><<<NRNA, blk, 0, stream>>>(
            rowptrR, NP1_R, evR,
            Tmp1 + (size_t)MP_RNA * 256, 256,
            Ybase, 256, nullptr, nullptr, out, 256, E);
        spmm_csr_kernel<64, 2><<<NPROT, blk, 0, stream>>>(
            rowptrP, NP1_P, evP,
            Tmp1, 256,
            Ybase + (size_t)MP_RNA * 256, 256, nullptr, nullptr,
            out + (size_t)NRNA * 256, 256, E);
    } else {
        spmm_csr_kernel<64, 0><<<NRNA, blk, 0, stream>>>(
            rowptrR, NP1_R, evR,
            Tmp1 + (size_t)MP_RNA * 256, 256,
            Ybase, 256, nullptr, nullptr, nullptr, 0, E);
        spmm_csr_kernel<64, 0><<<NPROT, blk, 0, stream>>>(
            rowptrP, NP1_P, evP,
            Tmp1, 256,
            Ybase + (size_t)MP_RNA * 256, 256, nullptr, nullptr, nullptr, 0, E);
        relu_out_kernel<<<(NRNA * 256) / 256, blk, 0, stream>>>(Ybase, out, NRNA);
        relu_out_kernel<<<(NPROT * 256) / 256, blk, 0, stream>>>(
            Ybase + (size_t)MP_RNA * 256, out + (size_t)NRNA * 256, NPROT);
    }
}